// Round 2
// baseline (7663.779 us; speedup 1.0000x reference)
//
#include <hip/hip_runtime.h>
#include <hip/hip_bf16.h>
#include <stdint.h>

// Problem constants (match reference)
#define N_PTS    32768
#define N_CLU    2048
#define DIM      512
#define DECAY    0.99f
#define EPS      1e-5f
#define NORM_EPS 1e-12f

// Output layout (flat f32, reference return order)
#define OUT_Q      0                          // quantized [N_PTS*DIM]
#define OUT_IDX    (N_PTS*DIM)                // indices   [N_PTS]
#define OUT_NEWC   (OUT_IDX + N_PTS)          // new_centroids [N_CLU*DIM]
#define OUT_SIZE   (OUT_NEWC + N_CLU*DIM)     // new_size  [N_CLU]
#define OUT_NEWW   (OUT_SIZE + N_CLU)         // new_w     [N_CLU*DIM]

// ---------------- init workspace ----------------
__global__ void init_kernel(unsigned long long* __restrict__ best,
                            int* __restrict__ counts,
                            int* __restrict__ cursor) {
    int i = blockIdx.x * blockDim.x + threadIdx.x;
    int stride = gridDim.x * blockDim.x;
    for (int j = i; j < N_PTS; j += stride) best[j] = 0xFFFFFFFFFFFFFFFFULL;
    for (int j = i; j < N_CLU; j += stride) { counts[j] = 0; cursor[j] = 0; }
}

// ---------------- row 1/norm of X (one wave per row) ----------------
__global__ void rownorm_kernel(const float* __restrict__ X,
                               float* __restrict__ rnorm) {
    int wave = (blockIdx.x * blockDim.x + threadIdx.x) >> 6;
    int lane = threadIdx.x & 63;
    if (wave >= N_PTS) return;
    const float4* xr = (const float4*)(X + (size_t)wave * DIM);
    float4 a = xr[lane];
    float4 b = xr[lane + 64];
    float ss = a.x*a.x + a.y*a.y + a.z*a.z + a.w*a.w
             + b.x*b.x + b.y*b.y + b.z*b.z + b.w*b.w;
    #pragma unroll
    for (int off = 32; off > 0; off >>= 1) ss += __shfl_xor(ss, off);
    if (lane == 0) rnorm[wave] = 1.0f / fmaxf(sqrtf(ss), NORM_EPS);
}

// ---------------- |c_k|^2 (one wave per centroid) ----------------
__global__ void cnorm_kernel(const float* __restrict__ C,
                             float* __restrict__ cnorm2) {
    int wave = (blockIdx.x * blockDim.x + threadIdx.x) >> 6;
    int lane = threadIdx.x & 63;
    if (wave >= N_CLU) return;
    const float4* cr = (const float4*)(C + (size_t)wave * DIM);
    float4 a = cr[lane];
    float4 b = cr[lane + 64];
    float ss = a.x*a.x + a.y*a.y + a.z*a.z + a.w*a.w
             + b.x*b.x + b.y*b.y + b.z*b.z + b.w*b.w;
    #pragma unroll
    for (int off = 32; off > 0; off >>= 1) ss += __shfl_xor(ss, off);
    if (lane == 0) cnorm2[wave] = ss;
}

// ---------------- fused fp32 GEMM + per-row argmin ----------------
// score[i][k] = |c_k|^2 - 2 * (Xn_i . c_k); argmin_k matches the reference
// distance argmin (|xn|^2 row-constant dropped). 128x128 tile, BK=16,
// 256 threads, 8x8 microtile. Per-row winner combined across N-tiles via
// u64 atomicMin on (order-encoded score << 32 | idx) — ties -> smallest idx,
// matching jnp.argmin.
#define BM 128
#define BN 128
#define BK 16

__global__ __launch_bounds__(256) void dist_argmin_kernel(
    const float* __restrict__ X, const float* __restrict__ C,
    const float* __restrict__ rnorm, const float* __restrict__ cnorm2,
    unsigned long long* __restrict__ best) {
    __shared__ float As[BK][BM];   // K-major
    __shared__ float Bs[BK][BN];

    const int tid = threadIdx.x;
    const int tx = tid & 15;
    const int ty = tid >> 4;
    const int m0 = blockIdx.x * BM;
    const int n0 = blockIdx.y * BN;

    // staging assignment is tid-invariant across k-chunks
    const int f0 = tid;         // float4 slot 0..255
    const int f1 = tid + 256;   // 256..511
    const int rowA0 = f0 >> 2, kq0 = f0 & 3;
    const int rowA1 = f1 >> 2, kq1 = f1 & 3;
    const float rs0 = rnorm[m0 + rowA0];
    const float rs1 = rnorm[m0 + rowA1];
    const float* Abase0 = X + (size_t)(m0 + rowA0) * DIM + kq0 * 4;
    const float* Abase1 = X + (size_t)(m0 + rowA1) * DIM + kq1 * 4;
    const float* Bbase0 = C + (size_t)(n0 + rowA0) * DIM + kq0 * 4;
    const float* Bbase1 = C + (size_t)(n0 + rowA1) * DIM + kq1 * 4;

    float acc[8][8];
    #pragma unroll
    for (int r = 0; r < 8; r++)
        #pragma unroll
        for (int c = 0; c < 8; c++) acc[r][c] = 0.0f;

    for (int c0 = 0; c0 < DIM; c0 += BK) {
        float4 va0 = *(const float4*)(Abase0 + c0);
        float4 va1 = *(const float4*)(Abase1 + c0);
        float4 vb0 = *(const float4*)(Bbase0 + c0);
        float4 vb1 = *(const float4*)(Bbase1 + c0);
        As[kq0*4+0][rowA0] = va0.x*rs0; As[kq0*4+1][rowA0] = va0.y*rs0;
        As[kq0*4+2][rowA0] = va0.z*rs0; As[kq0*4+3][rowA0] = va0.w*rs0;
        As[kq1*4+0][rowA1] = va1.x*rs1; As[kq1*4+1][rowA1] = va1.y*rs1;
        As[kq1*4+2][rowA1] = va1.z*rs1; As[kq1*4+3][rowA1] = va1.w*rs1;
        Bs[kq0*4+0][rowA0] = vb0.x; Bs[kq0*4+1][rowA0] = vb0.y;
        Bs[kq0*4+2][rowA0] = vb0.z; Bs[kq0*4+3][rowA0] = vb0.w;
        Bs[kq1*4+0][rowA1] = vb1.x; Bs[kq1*4+1][rowA1] = vb1.y;
        Bs[kq1*4+2][rowA1] = vb1.z; Bs[kq1*4+3][rowA1] = vb1.w;
        __syncthreads();

        #pragma unroll
        for (int t = 0; t < BK; t++) {
            float4 a0 = *(const float4*)&As[t][ty * 8];
            float4 a1 = *(const float4*)&As[t][ty * 8 + 4];
            float4 b0 = *(const float4*)&Bs[t][tx * 8];
            float4 b1 = *(const float4*)&Bs[t][tx * 8 + 4];
            float a[8] = {a0.x, a0.y, a0.z, a0.w, a1.x, a1.y, a1.z, a1.w};
            float b[8] = {b0.x, b0.y, b0.z, b0.w, b1.x, b1.y, b1.z, b1.w};
            #pragma unroll
            for (int r = 0; r < 8; r++)
                #pragma unroll
                for (int c = 0; c < 8; c++)
                    acc[r][c] = fmaf(a[r], b[c], acc[r][c]);
        }
        __syncthreads();
    }

    // epilogue: per-row argmin over this block's 128 columns
    #pragma unroll
    for (int r = 0; r < 8; r++) {
        float bs = INFINITY;
        int bi = 0x7FFFFFFF;
        #pragma unroll
        for (int c = 0; c < 8; c++) {
            int gc = n0 + tx * 8 + c;
            float s = cnorm2[gc] - 2.0f * acc[r][c];
            if (s < bs) { bs = s; bi = gc; }   // ascending c: first wins ties
        }
        unsigned u = __float_as_uint(bs);
        u = (u & 0x80000000u) ? ~u : (u | 0x80000000u);  // order-preserving
        unsigned long long p = ((unsigned long long)u << 32) | (unsigned)bi;
        #pragma unroll
        for (int off = 1; off < 16; off <<= 1) {
            unsigned long long q = __shfl_xor(p, off);
            if (q < p) p = q;
        }
        if (tx == 0) atomicMin(best + m0 + ty * 8 + r, p);
    }
}

// ---------------- decode winners, histogram ----------------
__global__ void decode_kernel(const unsigned long long* __restrict__ best,
                              int* __restrict__ idxs,
                              float* __restrict__ out_idx,
                              int* __restrict__ counts) {
    int i = blockIdx.x * blockDim.x + threadIdx.x;
    if (i >= N_PTS) return;
    int idx = (int)(unsigned)(best[i] & 0xFFFFFFFFu);
    idxs[i] = idx;
    out_idx[i] = (float)idx;
    atomicAdd(&counts[idx], 1);
}

// ---------------- quantized = centroids[idx] (one wave per row) ----------------
__global__ void quant_kernel(const float* __restrict__ C,
                             const int* __restrict__ idxs,
                             float* __restrict__ outq) {
    int wave = (blockIdx.x * blockDim.x + threadIdx.x) >> 6;
    int lane = threadIdx.x & 63;
    if (wave >= N_PTS) return;
    int idx = idxs[wave];
    const float4* src = (const float4*)(C + (size_t)idx * DIM);
    float4* dst = (float4*)(outq + (size_t)wave * DIM);
    dst[lane] = src[lane];
    dst[lane + 64] = src[lane + 64];
}

// ---------------- exclusive prefix sum of counts (single block) ----------------
__global__ __launch_bounds__(1024) void scan_kernel(const int* __restrict__ counts,
                                                    int* __restrict__ offsets) {
    __shared__ int bufA[N_CLU];
    __shared__ int bufB[N_CLU];
    int t = threadIdx.x;
    bufA[t] = counts[t];
    bufA[t + 1024] = counts[t + 1024];
    __syncthreads();
    int* src = bufA;
    int* dst = bufB;
    for (int d = 1; d < N_CLU; d <<= 1) {
        for (int i = t; i < N_CLU; i += 1024) {
            int v = src[i];
            if (i >= d) v += src[i - d];
            dst[i] = v;
        }
        __syncthreads();
        int* tmp = src; src = dst; dst = tmp;
    }
    // src holds inclusive scan
    for (int i = t; i < N_CLU; i += 1024)
        offsets[i] = (i == 0) ? 0 : src[i - 1];
}

// ---------------- bucket placement (counting sort, atomic rank) ----------------
__global__ void place_kernel(const int* __restrict__ idxs,
                             const int* __restrict__ offsets,
                             int* __restrict__ cursor,
                             int* __restrict__ bucket) {
    int i = blockIdx.x * blockDim.x + threadIdx.x;
    if (i >= N_PTS) return;
    int k = idxs[i];
    int r = atomicAdd(&cursor[k], 1);
    bucket[offsets[k] + r] = i;
}

// ---------------- new_size (single block) ----------------
__global__ __launch_bounds__(1024) void newsize_kernel(
    const float* __restrict__ ema_size, const int* __restrict__ counts,
    float* __restrict__ out_size) {
    __shared__ float red[16];
    __shared__ float nval;
    int t = threadIdx.x;
    float p0 = ema_size[t] * DECAY + (1.0f - DECAY) * (float)counts[t];
    float p1 = ema_size[t + 1024] * DECAY + (1.0f - DECAY) * (float)counts[t + 1024];
    float s = p0 + p1;
    #pragma unroll
    for (int off = 32; off > 0; off >>= 1) s += __shfl_xor(s, off);
    if ((t & 63) == 0) red[t >> 6] = s;
    __syncthreads();
    if (t == 0) {
        float n = 0.0f;
        for (int i = 0; i < 16; i++) n += red[i];
        nval = n;
    }
    __syncthreads();
    float n = nval;
    float denom = n + (float)N_CLU * EPS;
    out_size[t]        = (p0 + EPS) / denom * n;
    out_size[t + 1024] = (p1 + EPS) / denom * n;
}

// ---------------- fused dw gather + new_w + new_centroids ----------------
// One block (256 threads, float2 each) per cluster. Sums the X rows of the
// cluster's assigned points (bucketed gather — no fp32 atomics), then applies
// the EMA update and division in-register.
__global__ __launch_bounds__(256) void update_kernel(
    const float* __restrict__ X, const int* __restrict__ bucket,
    const int* __restrict__ offsets, const int* __restrict__ counts,
    const float* __restrict__ ema_w, const float* __restrict__ new_size,
    float* __restrict__ out_neww, float* __restrict__ out_newc) {
    int k = blockIdx.x;
    int t = threadIdx.x;
    int cnt = counts[k];
    int base = offsets[k];
    float accx = 0.0f, accy = 0.0f;
    for (int j = 0; j < cnt; j++) {
        int p = bucket[base + j];
        float2 v = *(const float2*)(X + (size_t)p * DIM + t * 2);
        accx += v.x; accy += v.y;
    }
    size_t e = (size_t)k * DIM + t * 2;
    float2 w = *(const float2*)(ema_w + e);
    float inv = 1.0f / new_size[k];
    float nw0 = w.x * DECAY + (1.0f - DECAY) * accx;
    float nw1 = w.y * DECAY + (1.0f - DECAY) * accy;
    float2 outw = {nw0, nw1};
    float2 outc = {nw0 * inv, nw1 * inv};
    *(float2*)(out_neww + e) = outw;
    *(float2*)(out_newc + e) = outc;
}

extern "C" void kernel_launch(void* const* d_in, const int* in_sizes, int n_in,
                              void* d_out, int out_size, void* d_ws, size_t ws_size,
                              hipStream_t stream) {
    const float* X        = (const float*)d_in[0];
    const float* C        = (const float*)d_in[1];
    const float* ema_size = (const float*)d_in[2];
    const float* ema_w    = (const float*)d_in[3];
    float* out = (float*)d_out;

    float* out_q    = out + OUT_Q;
    float* out_idx  = out + OUT_IDX;
    float* out_newc = out + OUT_NEWC;
    float* out_sizep= out + OUT_SIZE;
    float* out_neww = out + OUT_NEWW;

    // workspace layout (8B-aligned head)
    char* ws = (char*)d_ws;
    unsigned long long* best = (unsigned long long*)ws;           // 256 KiB
    float* rnorm  = (float*)(ws + N_PTS * 8);                     // 128 KiB
    float* cnorm2 = rnorm + N_PTS;                                // 8 KiB
    int*   idxs   = (int*)(cnorm2 + N_CLU);                       // 128 KiB
    int*   counts = idxs + N_PTS;                                 // 8 KiB
    int*   offsets= counts + N_CLU;                               // 8 KiB
    int*   cursor = offsets + N_CLU;                              // 8 KiB
    int*   bucket = cursor + N_CLU;                               // 128 KiB

    init_kernel<<<512, 256, 0, stream>>>(best, counts, cursor);
    rownorm_kernel<<<N_PTS / 4, 256, 0, stream>>>(X, rnorm);
    cnorm_kernel<<<N_CLU / 4, 256, 0, stream>>>(C, cnorm2);

    dim3 grid(N_PTS / BM, N_CLU / BN);
    dist_argmin_kernel<<<grid, 256, 0, stream>>>(X, C, rnorm, cnorm2, best);

    decode_kernel<<<(N_PTS + 255) / 256, 256, 0, stream>>>(best, idxs, out_idx, counts);
    quant_kernel<<<N_PTS / 4, 256, 0, stream>>>(C, idxs, out_q);
    newsize_kernel<<<1, 1024, 0, stream>>>(ema_size, counts, out_sizep);
    scan_kernel<<<1, 1024, 0, stream>>>(counts, offsets);
    place_kernel<<<(N_PTS + 255) / 256, 256, 0, stream>>>(idxs, offsets, cursor, bucket);
    update_kernel<<<N_CLU, 256, 0, stream>>>(X, bucket, offsets, counts,
                                             ema_w, out_sizep, out_neww, out_newc);
}

// Round 3
// 1481.885 us; speedup vs baseline: 5.1716x; 5.1716x over previous
//
#include <hip/hip_runtime.h>
#include <hip/hip_bf16.h>
#include <stdint.h>

// Problem constants (match reference)
#define N_PTS    32768
#define N_CLU    2048
#define DIM      512
#define DECAY    0.99f
#define EPS      1e-5f
#define NORM_EPS 1e-12f

// Output layout (flat f32, reference return order)
#define OUT_Q      0                          // quantized [N_PTS*DIM]
#define OUT_IDX    (N_PTS*DIM)                // indices   [N_PTS]
#define OUT_NEWC   (OUT_IDX + N_PTS)          // new_centroids [N_CLU*DIM]
#define OUT_SIZE   (OUT_NEWC + N_CLU*DIM)     // new_size  [N_CLU]
#define OUT_NEWW   (OUT_SIZE + N_CLU)         // new_w     [N_CLU*DIM]

// ---------------- init workspace ----------------
__global__ void init_kernel(unsigned long long* __restrict__ best,
                            int* __restrict__ counts,
                            int* __restrict__ cursor,
                            float* __restrict__ dw) {
    int i = blockIdx.x * blockDim.x + threadIdx.x;
    int stride = gridDim.x * blockDim.x;
    for (int j = i; j < N_PTS; j += stride) best[j] = 0xFFFFFFFFFFFFFFFFULL;
    for (int j = i; j < N_CLU; j += stride) { counts[j] = 0; cursor[j] = 0; }
    for (int j = i; j < N_CLU * DIM; j += stride) dw[j] = 0.0f;
}

// ---------------- row 1/norm of X (one wave per row) ----------------
__global__ void rownorm_kernel(const float* __restrict__ X,
                               float* __restrict__ rnorm) {
    int wave = (blockIdx.x * blockDim.x + threadIdx.x) >> 6;
    int lane = threadIdx.x & 63;
    if (wave >= N_PTS) return;
    const float4* xr = (const float4*)(X + (size_t)wave * DIM);
    float4 a = xr[lane];
    float4 b = xr[lane + 64];
    float ss = a.x*a.x + a.y*a.y + a.z*a.z + a.w*a.w
             + b.x*b.x + b.y*b.y + b.z*b.z + b.w*b.w;
    #pragma unroll
    for (int off = 32; off > 0; off >>= 1) ss += __shfl_xor(ss, off);
    if (lane == 0) rnorm[wave] = 1.0f / fmaxf(sqrtf(ss), NORM_EPS);
}

// ---------------- |c_k|^2 (one wave per centroid) ----------------
__global__ void cnorm_kernel(const float* __restrict__ C,
                             float* __restrict__ cnorm2) {
    int wave = (blockIdx.x * blockDim.x + threadIdx.x) >> 6;
    int lane = threadIdx.x & 63;
    if (wave >= N_CLU) return;
    const float4* cr = (const float4*)(C + (size_t)wave * DIM);
    float4 a = cr[lane];
    float4 b = cr[lane + 64];
    float ss = a.x*a.x + a.y*a.y + a.z*a.z + a.w*a.w
             + b.x*b.x + b.y*b.y + b.z*b.z + b.w*b.w;
    #pragma unroll
    for (int off = 32; off > 0; off >>= 1) ss += __shfl_xor(ss, off);
    if (lane == 0) cnorm2[wave] = ss;
}

// ---------------- fused fp32 GEMM + per-row argmin ----------------
#define BM 128
#define BN 128
#define BK 16

__global__ __launch_bounds__(256) void dist_argmin_kernel(
    const float* __restrict__ X, const float* __restrict__ C,
    const float* __restrict__ rnorm, const float* __restrict__ cnorm2,
    unsigned long long* __restrict__ best) {
    __shared__ float As[BK][BM];   // K-major
    __shared__ float Bs[BK][BN];

    const int tid = threadIdx.x;
    const int tx = tid & 15;
    const int ty = tid >> 4;
    const int m0 = blockIdx.x * BM;
    const int n0 = blockIdx.y * BN;

    const int f0 = tid;
    const int f1 = tid + 256;
    const int rowA0 = f0 >> 2, kq0 = f0 & 3;
    const int rowA1 = f1 >> 2, kq1 = f1 & 3;
    const float rs0 = rnorm[m0 + rowA0];
    const float rs1 = rnorm[m0 + rowA1];
    const float* Abase0 = X + (size_t)(m0 + rowA0) * DIM + kq0 * 4;
    const float* Abase1 = X + (size_t)(m0 + rowA1) * DIM + kq1 * 4;
    const float* Bbase0 = C + (size_t)(n0 + rowA0) * DIM + kq0 * 4;
    const float* Bbase1 = C + (size_t)(n0 + rowA1) * DIM + kq1 * 4;

    float acc[8][8];
    #pragma unroll
    for (int r = 0; r < 8; r++)
        #pragma unroll
        for (int c = 0; c < 8; c++) acc[r][c] = 0.0f;

    for (int c0 = 0; c0 < DIM; c0 += BK) {
        float4 va0 = *(const float4*)(Abase0 + c0);
        float4 va1 = *(const float4*)(Abase1 + c0);
        float4 vb0 = *(const float4*)(Bbase0 + c0);
        float4 vb1 = *(const float4*)(Bbase1 + c0);
        As[kq0*4+0][rowA0] = va0.x*rs0; As[kq0*4+1][rowA0] = va0.y*rs0;
        As[kq0*4+2][rowA0] = va0.z*rs0; As[kq0*4+3][rowA0] = va0.w*rs0;
        As[kq1*4+0][rowA1] = va1.x*rs1; As[kq1*4+1][rowA1] = va1.y*rs1;
        As[kq1*4+2][rowA1] = va1.z*rs1; As[kq1*4+3][rowA1] = va1.w*rs1;
        Bs[kq0*4+0][rowA0] = vb0.x; Bs[kq0*4+1][rowA0] = vb0.y;
        Bs[kq0*4+2][rowA0] = vb0.z; Bs[kq0*4+3][rowA0] = vb0.w;
        Bs[kq1*4+0][rowA1] = vb1.x; Bs[kq1*4+1][rowA1] = vb1.y;
        Bs[kq1*4+2][rowA1] = vb1.z; Bs[kq1*4+3][rowA1] = vb1.w;
        __syncthreads();

        #pragma unroll
        for (int t = 0; t < BK; t++) {
            float4 a0 = *(const float4*)&As[t][ty * 8];
            float4 a1 = *(const float4*)&As[t][ty * 8 + 4];
            float4 b0 = *(const float4*)&Bs[t][tx * 8];
            float4 b1 = *(const float4*)&Bs[t][tx * 8 + 4];
            float a[8] = {a0.x, a0.y, a0.z, a0.w, a1.x, a1.y, a1.z, a1.w};
            float b[8] = {b0.x, b0.y, b0.z, b0.w, b1.x, b1.y, b1.z, b1.w};
            #pragma unroll
            for (int r = 0; r < 8; r++)
                #pragma unroll
                for (int c = 0; c < 8; c++)
                    acc[r][c] = fmaf(a[r], b[c], acc[r][c]);
        }
        __syncthreads();
    }

    #pragma unroll
    for (int r = 0; r < 8; r++) {
        float bs = INFINITY;
        int bi = 0x7FFFFFFF;
        #pragma unroll
        for (int c = 0; c < 8; c++) {
            int gc = n0 + tx * 8 + c;
            float s = cnorm2[gc] - 2.0f * acc[r][c];
            if (s < bs) { bs = s; bi = gc; }   // ascending c: first wins ties
        }
        unsigned u = __float_as_uint(bs);
        u = (u & 0x80000000u) ? ~u : (u | 0x80000000u);  // order-preserving
        unsigned long long p = ((unsigned long long)u << 32) | (unsigned)bi;
        #pragma unroll
        for (int off = 1; off < 16; off <<= 1) {
            unsigned long long q = __shfl_xor(p, off);
            if (q < p) p = q;
        }
        if (tx == 0) atomicMin(best + m0 + ty * 8 + r, p);
    }
}

// ---------------- decode winners, histogram (wave-aggregated) ----------------
__global__ void decode_kernel(const unsigned long long* __restrict__ best,
                              int* __restrict__ idxs,
                              float* __restrict__ out_idx,
                              int* __restrict__ counts) {
    int i = blockIdx.x * blockDim.x + threadIdx.x;
    if (i >= N_PTS) return;
    int lane = threadIdx.x & 63;
    int idx = (int)(unsigned)(best[i] & 0xFFFFFFFFu);
    idxs[i] = idx;
    out_idx[i] = (float)idx;
    // fast path: all 64 lanes same cluster (common under skew)
    int k0 = __shfl(idx, 0);
    unsigned long long same = __ballot(idx == k0);
    if (same == 0xFFFFFFFFFFFFFFFFULL) {
        if (lane == 0) atomicAdd(&counts[idx], 64);
    } else {
        atomicAdd(&counts[idx], 1);
    }
}

// ---------------- quantized = centroids[idx] (one wave per row) ----------------
__global__ void quant_kernel(const float* __restrict__ C,
                             const int* __restrict__ idxs,
                             float* __restrict__ outq) {
    int wave = (blockIdx.x * blockDim.x + threadIdx.x) >> 6;
    int lane = threadIdx.x & 63;
    if (wave >= N_PTS) return;
    int idx = idxs[wave];
    const float4* src = (const float4*)(C + (size_t)idx * DIM);
    float4* dst = (float4*)(outq + (size_t)wave * DIM);
    dst[lane] = src[lane];
    dst[lane + 64] = src[lane + 64];
}

// ---------------- exclusive prefix sum of counts (single block) ----------------
__global__ __launch_bounds__(1024) void scan_kernel(const int* __restrict__ counts,
                                                    int* __restrict__ offsets) {
    __shared__ int bufA[N_CLU];
    __shared__ int bufB[N_CLU];
    int t = threadIdx.x;
    bufA[t] = counts[t];
    bufA[t + 1024] = counts[t + 1024];
    __syncthreads();
    int* src = bufA;
    int* dst = bufB;
    for (int d = 1; d < N_CLU; d <<= 1) {
        for (int i = t; i < N_CLU; i += 1024) {
            int v = src[i];
            if (i >= d) v += src[i - d];
            dst[i] = v;
        }
        __syncthreads();
        int* tmp = src; src = dst; dst = tmp;
    }
    for (int i = t; i < N_CLU; i += 1024)
        offsets[i] = (i == 0) ? 0 : src[i - 1];
}

// ---------------- bucket placement (counting sort, wave-aggregated rank) -----
__global__ void place_kernel(const int* __restrict__ idxs,
                             const int* __restrict__ offsets,
                             int* __restrict__ cursor,
                             int* __restrict__ bucket,
                             int* __restrict__ bkey) {
    int i = blockIdx.x * blockDim.x + threadIdx.x;
    if (i >= N_PTS) return;
    int lane = threadIdx.x & 63;
    int k = idxs[i];
    int k0 = __shfl(k, 0);
    unsigned long long same = __ballot(k == k0);
    int pos;
    if (same == 0xFFFFFFFFFFFFFFFFULL) {
        int base = 0;
        if (lane == 0) base = atomicAdd(&cursor[k], 64);
        base = __shfl(base, 0);
        pos = offsets[k] + base + lane;
    } else {
        int r = atomicAdd(&cursor[k], 1);
        pos = offsets[k] + r;
    }
    bucket[pos] = i;
    bkey[pos] = k;
}

// ---------------- new_size (single block) ----------------
__global__ __launch_bounds__(1024) void newsize_kernel(
    const float* __restrict__ ema_size, const int* __restrict__ counts,
    float* __restrict__ out_size) {
    __shared__ float red[16];
    __shared__ float nval;
    int t = threadIdx.x;
    float p0 = ema_size[t] * DECAY + (1.0f - DECAY) * (float)counts[t];
    float p1 = ema_size[t + 1024] * DECAY + (1.0f - DECAY) * (float)counts[t + 1024];
    float s = p0 + p1;
    #pragma unroll
    for (int off = 32; off > 0; off >>= 1) s += __shfl_xor(s, off);
    if ((t & 63) == 0) red[t >> 6] = s;
    __syncthreads();
    if (t == 0) {
        float n = 0.0f;
        for (int i = 0; i < 16; i++) n += red[i];
        nval = n;
    }
    __syncthreads();
    float n = nval;
    float denom = n + (float)N_CLU * EPS;
    out_size[t]        = (p0 + EPS) / denom * n;
    out_size[t + 1024] = (p1 + EPS) / denom * n;
}

// ---------------- dw: chunked segmented reduction over sorted bucket --------
// 512 blocks × 64 sorted entries each; registers accumulate per-segment runs,
// one fp32-atomic flush per segment boundary. Work-proportional regardless of
// cluster-size skew.
#define CHUNK 64
__global__ __launch_bounds__(256) void dw_kernel(
    const float* __restrict__ X, const int* __restrict__ bucket,
    const int* __restrict__ bkey, float* __restrict__ dw) {
    int c0 = blockIdx.x * CHUNK;
    int t = threadIdx.x;             // 256 threads × float2 = 512 floats
    float accx = 0.0f, accy = 0.0f;
    int prevk = bkey[c0];
    for (int j = 0; j < CHUNK; j++) {
        int pos = c0 + j;
        int k = bkey[pos];
        if (k != prevk) {
            atomicAdd(&dw[(size_t)prevk * DIM + t * 2 + 0], accx);
            atomicAdd(&dw[(size_t)prevk * DIM + t * 2 + 1], accy);
            accx = 0.0f; accy = 0.0f;
            prevk = k;
        }
        int p = bucket[pos];
        float2 v = *(const float2*)(X + (size_t)p * DIM + t * 2);
        accx += v.x; accy += v.y;
    }
    atomicAdd(&dw[(size_t)prevk * DIM + t * 2 + 0], accx);
    atomicAdd(&dw[(size_t)prevk * DIM + t * 2 + 1], accy);
}

// ---------------- new_w, new_centroids ----------------
__global__ void final_kernel(const float* __restrict__ ema_w,
                             const float* __restrict__ dw,
                             const float* __restrict__ new_size,
                             float* __restrict__ out_neww,
                             float* __restrict__ out_newc) {
    int e = blockIdx.x * blockDim.x + threadIdx.x;
    if (e >= N_CLU * DIM) return;
    int k = e >> 9;  // /DIM
    float nw = ema_w[e] * DECAY + (1.0f - DECAY) * dw[e];
    out_neww[e] = nw;
    out_newc[e] = nw / new_size[k];
}

extern "C" void kernel_launch(void* const* d_in, const int* in_sizes, int n_in,
                              void* d_out, int out_size, void* d_ws, size_t ws_size,
                              hipStream_t stream) {
    const float* X        = (const float*)d_in[0];
    const float* C        = (const float*)d_in[1];
    const float* ema_size = (const float*)d_in[2];
    const float* ema_w    = (const float*)d_in[3];
    float* out = (float*)d_out;

    float* out_q    = out + OUT_Q;
    float* out_idx  = out + OUT_IDX;
    float* out_newc = out + OUT_NEWC;
    float* out_sizep= out + OUT_SIZE;
    float* out_neww = out + OUT_NEWW;

    // workspace layout (8B-aligned head)
    char* ws = (char*)d_ws;
    unsigned long long* best = (unsigned long long*)ws;           // 256 KiB
    float* rnorm  = (float*)(ws + N_PTS * 8);                     // 128 KiB
    float* cnorm2 = rnorm + N_PTS;                                // 8 KiB
    int*   idxs   = (int*)(cnorm2 + N_CLU);                       // 128 KiB
    int*   counts = idxs + N_PTS;                                 // 8 KiB
    int*   offsets= counts + N_CLU;                               // 8 KiB
    int*   cursor = offsets + N_CLU;                              // 8 KiB
    int*   bucket = cursor + N_CLU;                               // 128 KiB
    int*   bkey   = bucket + N_PTS;                               // 128 KiB
    float* dw     = (float*)(bkey + N_PTS);                       // 4 MiB

    init_kernel<<<2048, 256, 0, stream>>>(best, counts, cursor, dw);
    rownorm_kernel<<<N_PTS / 4, 256, 0, stream>>>(X, rnorm);
    cnorm_kernel<<<N_CLU / 4, 256, 0, stream>>>(C, cnorm2);

    dim3 grid(N_PTS / BM, N_CLU / BN);
    dist_argmin_kernel<<<grid, 256, 0, stream>>>(X, C, rnorm, cnorm2, best);

    decode_kernel<<<(N_PTS + 255) / 256, 256, 0, stream>>>(best, idxs, out_idx, counts);
    quant_kernel<<<N_PTS / 4, 256, 0, stream>>>(C, idxs, out_q);
    newsize_kernel<<<1, 1024, 0, stream>>>(ema_size, counts, out_sizep);
    scan_kernel<<<1, 1024, 0, stream>>>(counts, offsets);
    place_kernel<<<(N_PTS + 255) / 256, 256, 0, stream>>>(idxs, offsets, cursor, bucket, bkey);
    dw_kernel<<<N_PTS / CHUNK, 256, 0, stream>>>(X, bucket, bkey, dw);
    final_kernel<<<(N_CLU * DIM) / 256, 256, 0, stream>>>(ema_w, dw, out_sizep, out_neww, out_newc);
}

// Round 5
// 1451.614 us; speedup vs baseline: 5.2795x; 1.0209x over previous
//
#include <hip/hip_runtime.h>
#include <hip/hip_bf16.h>
#include <stdint.h>

// Problem constants (match reference)
#define N_PTS    32768
#define N_CLU    2048
#define DIM      512
#define DECAY    0.99f
#define EPS      1e-5f
#define NORM_EPS 1e-12f
#define MARGIN   0.02f   // score-gap threshold for exact fp32 re-check (~10 sigma of fp16 error)

// Output layout (flat f32, reference return order)
#define OUT_Q      0
#define OUT_IDX    (N_PTS*DIM)
#define OUT_NEWC   (OUT_IDX + N_PTS)
#define OUT_SIZE   (OUT_NEWC + N_CLU*DIM)
#define OUT_NEWW   (OUT_SIZE + N_CLU)

typedef _Float16 half8 __attribute__((ext_vector_type(8)));
typedef float f32x4 __attribute__((ext_vector_type(4)));

union H8 { _Float16 h[8]; uint4 u; };

// order-preserving f32 -> u32 encode (min-compatible), and decode
__device__ __forceinline__ unsigned enc_f32(float f) {
    unsigned u = __float_as_uint(f);
    return (u & 0x80000000u) ? ~u : (u | 0x80000000u);
}
__device__ __forceinline__ float dec_f32(unsigned e) {
    unsigned u = (e & 0x80000000u) ? (e & 0x7FFFFFFFu) : ~e;
    return __uint_as_float(u);
}

// ---------------- init workspace ----------------
__global__ void init_kernel(int* __restrict__ counts,
                            int* __restrict__ cursor,
                            int* __restrict__ wl_cnt,
                            float* __restrict__ dw) {
    int i = blockIdx.x * blockDim.x + threadIdx.x;
    int stride = gridDim.x * blockDim.x;
    if (i == 0) wl_cnt[0] = 0;
    for (int j = i; j < N_CLU; j += stride) { counts[j] = 0; cursor[j] = 0; }
    for (int j = i; j < N_CLU * DIM; j += stride) dw[j] = 0.0f;
}

// ---------------- rnorm + normalized X in fp16 (one wave per row) ----------
__global__ void prep_x_kernel(const float* __restrict__ X,
                              float* __restrict__ rnorm,
                              _Float16* __restrict__ Xh) {
    int row = (blockIdx.x * blockDim.x + threadIdx.x) >> 6;
    int lane = threadIdx.x & 63;
    if (row >= N_PTS) return;
    const float4* xr = (const float4*)(X + (size_t)row * DIM);
    float4 a = xr[2 * lane];
    float4 b = xr[2 * lane + 1];
    float ss = a.x*a.x + a.y*a.y + a.z*a.z + a.w*a.w
             + b.x*b.x + b.y*b.y + b.z*b.z + b.w*b.w;
    #pragma unroll
    for (int off = 32; off > 0; off >>= 1) ss += __shfl_xor(ss, off);
    float rs = 1.0f / fmaxf(sqrtf(ss), NORM_EPS);
    if (lane == 0) rnorm[row] = rs;
    H8 o;
    o.h[0] = (_Float16)(a.x * rs); o.h[1] = (_Float16)(a.y * rs);
    o.h[2] = (_Float16)(a.z * rs); o.h[3] = (_Float16)(a.w * rs);
    o.h[4] = (_Float16)(b.x * rs); o.h[5] = (_Float16)(b.y * rs);
    o.h[6] = (_Float16)(b.z * rs); o.h[7] = (_Float16)(b.w * rs);
    *(uint4*)(Xh + (size_t)row * DIM + lane * 8) = o.u;
}

// ---------------- |c|^2 + C in fp16 (one wave per centroid) ----------------
__global__ void prep_c_kernel(const float* __restrict__ C,
                              float* __restrict__ cnorm2,
                              _Float16* __restrict__ Ch) {
    int row = (blockIdx.x * blockDim.x + threadIdx.x) >> 6;
    int lane = threadIdx.x & 63;
    if (row >= N_CLU) return;
    const float4* cr = (const float4*)(C + (size_t)row * DIM);
    float4 a = cr[2 * lane];
    float4 b = cr[2 * lane + 1];
    float ss = a.x*a.x + a.y*a.y + a.z*a.z + a.w*a.w
             + b.x*b.x + b.y*b.y + b.z*b.z + b.w*b.w;
    #pragma unroll
    for (int off = 32; off > 0; off >>= 1) ss += __shfl_xor(ss, off);
    if (lane == 0) cnorm2[row] = ss;
    H8 o;
    o.h[0] = (_Float16)a.x; o.h[1] = (_Float16)a.y;
    o.h[2] = (_Float16)a.z; o.h[3] = (_Float16)a.w;
    o.h[4] = (_Float16)b.x; o.h[5] = (_Float16)b.y;
    o.h[6] = (_Float16)b.z; o.h[7] = (_Float16)b.w;
    *(uint4*)(Ch + (size_t)row * DIM + lane * 8) = o.u;
}

// ---------------- MFMA fp16 GEMM + per-row per-(tile,wc) top-2 -------------
// 128x128 tile, BK=32, 4 waves in (wr,wc) 64x64 quadrants, 4x4 frags of
// 16x16x32. LDS unpadded [128][32] halves (m97-proportioned layout).
// Each wave writes its row top-2 into slot (blockIdx.y*2 + wc) -> every slot
// has exactly ONE writer (fixes the R4 two-waves-same-slot race).
#define TBM 128
#define TBN 128
#define TBK 32
#define LDS_S 32

__global__ __launch_bounds__(256) void dist_mfma_kernel(
    const _Float16* __restrict__ Xh, const _Float16* __restrict__ Ch,
    const float* __restrict__ cnorm2,
    unsigned long long* __restrict__ tile2) {
    __shared__ _Float16 Ah[TBM * LDS_S];
    __shared__ _Float16 Bh[TBN * LDS_S];

    const int tid = threadIdx.x;
    const int m0 = blockIdx.x * TBM;
    const int n0 = blockIdx.y * TBN;

    const int wid = tid >> 6;
    const int l = tid & 63;
    const int wr = wid >> 1, wc = wid & 1;
    const int lr = l & 15, g = l >> 4;

    // staging: thread t handles row=t>>1, khalf=t&1 (16 halves = 32B)
    const int srow = tid >> 1, shalf = tid & 1;
    const _Float16* srcA = Xh + (size_t)(m0 + srow) * DIM + shalf * 16;
    const _Float16* srcB = Ch + (size_t)(n0 + srow) * DIM + shalf * 16;
    _Float16* dstA = &Ah[srow * LDS_S + shalf * 16];
    _Float16* dstB = &Bh[srow * LDS_S + shalf * 16];

    f32x4 acc[4][4];
    #pragma unroll
    for (int m = 0; m < 4; m++)
        #pragma unroll
        for (int n = 0; n < 4; n++) acc[m][n] = (f32x4){0.f, 0.f, 0.f, 0.f};

    for (int k0 = 0; k0 < DIM; k0 += TBK) {
        const uint4* pa = (const uint4*)(srcA + k0);
        const uint4* pb = (const uint4*)(srcB + k0);
        uint4 a0 = pa[0], a1 = pa[1];
        uint4 b0 = pb[0], b1 = pb[1];
        *(uint4*)dstA = a0; *(uint4*)(dstA + 8) = a1;
        *(uint4*)dstB = b0; *(uint4*)(dstB + 8) = b1;
        __syncthreads();

        half8 af[4], bf[4];
        #pragma unroll
        for (int m = 0; m < 4; m++)
            af[m] = *(const half8*)&Ah[(wr * 64 + m * 16 + lr) * LDS_S + g * 8];
        #pragma unroll
        for (int n = 0; n < 4; n++)
            bf[n] = *(const half8*)&Bh[(wc * 64 + n * 16 + lr) * LDS_S + g * 8];
        #pragma unroll
        for (int m = 0; m < 4; m++)
            #pragma unroll
            for (int n = 0; n < 4; n++)
                acc[m][n] = __builtin_amdgcn_mfma_f32_16x16x32_f16(af[m], bf[n], acc[m][n], 0, 0, 0);
        __syncthreads();
    }

    // epilogue: per-row top-2 across this wave's 64 columns
    float cn2[4];
    int coln[4];
    #pragma unroll
    for (int n = 0; n < 4; n++) {
        coln[n] = n0 + wc * 64 + n * 16 + lr;
        cn2[n] = cnorm2[coln[n]];
    }
    const int slot = blockIdx.y * 2 + wc;
    #pragma unroll
    for (int m = 0; m < 4; m++) {
        #pragma unroll
        for (int reg = 0; reg < 4; reg++) {
            unsigned long long b1 = ~0ULL, b2 = ~0ULL;
            #pragma unroll
            for (int n = 0; n < 4; n++) {
                float s = cn2[n] - 2.0f * acc[m][n][reg];
                unsigned long long p =
                    ((unsigned long long)enc_f32(s) << 32) | (unsigned)coln[n];
                if (p < b1) { b2 = b1; b1 = p; }
                else if (p < b2) { b2 = p; }
            }
            #pragma unroll
            for (int off = 1; off < 16; off <<= 1) {
                unsigned long long c1 = __shfl_xor(b1, off);
                unsigned long long c2 = __shfl_xor(b2, off);
                if (c1 < b1) { b2 = (b1 < c2) ? b1 : c2; b1 = c1; }
                else         { b2 = (b2 < c1) ? b2 : c1; }
            }
            if (lr == 0) {
                int R = m0 + wr * 64 + m * 16 + g * 4 + reg;
                size_t o = ((size_t)slot * N_PTS + R) * 2;
                tile2[o] = b1;
                tile2[o + 1] = b2;
            }
        }
    }
}

// ---------------- global top-2 reduce + margin flag ----------------
__global__ void reduce_kernel(const unsigned long long* __restrict__ tile2,
                              int* __restrict__ idxs,
                              int* __restrict__ wl, int* __restrict__ wl_cnt) {
    int i = blockIdx.x * blockDim.x + threadIdx.x;
    if (i >= N_PTS) return;
    unsigned long long b1 = ~0ULL, b2 = ~0ULL;
    #pragma unroll
    for (int j = 0; j < 32; j++) {
        size_t o = ((size_t)j * N_PTS + i) * 2;
        unsigned long long c1 = tile2[o], c2 = tile2[o + 1];
        if (c1 < b1) { b2 = (b1 < c2) ? b1 : c2; b1 = c1; }
        else         { b2 = (b2 < c1) ? b2 : c1; }
    }
    idxs[i] = (int)(unsigned)(b1 & 0xFFFFFFFFu);
    float gap = dec_f32((unsigned)(b2 >> 32)) - dec_f32((unsigned)(b1 >> 32));
    if (gap < MARGIN) {
        int pos = atomicAdd(wl_cnt, 1);
        wl[pos] = i;
    }
}

// ---------------- exact fp32 argmin for flagged rows ----------------
__global__ __launch_bounds__(256) void exact_kernel(
    const float* __restrict__ X, const float* __restrict__ C,
    const float* __restrict__ rnorm, const float* __restrict__ cnorm2,
    const int* __restrict__ wl, const int* __restrict__ wl_cnt,
    int* __restrict__ idxs) {
    int gw = (blockIdx.x * blockDim.x + threadIdx.x) >> 6;
    int lane = threadIdx.x & 63;
    int n = wl_cnt[0];
    for (int it = gw; it < n; it += 1024) {
        int i = wl[it];
        float rs = rnorm[i];
        const float4* xr = (const float4*)(X + (size_t)i * DIM);
        float4 xa = xr[2 * lane], xb = xr[2 * lane + 1];
        xa.x *= rs; xa.y *= rs; xa.z *= rs; xa.w *= rs;
        xb.x *= rs; xb.y *= rs; xb.z *= rs; xb.w *= rs;
        unsigned long long best = ~0ULL;
        for (int k = 0; k < N_CLU; k++) {
            const float4* cr = (const float4*)(C + (size_t)k * DIM);
            float4 ca = cr[2 * lane], cb = cr[2 * lane + 1];
            float d = xa.x*ca.x + xa.y*ca.y + xa.z*ca.z + xa.w*ca.w
                    + xb.x*cb.x + xb.y*cb.y + xb.z*cb.z + xb.w*cb.w;
            #pragma unroll
            for (int off = 32; off > 0; off >>= 1) d += __shfl_xor(d, off);
            float s = cnorm2[k] - 2.0f * d;
            unsigned long long p =
                ((unsigned long long)enc_f32(s) << 32) | (unsigned)k;
            if (p < best) best = p;
        }
        if (lane == 0) idxs[i] = (int)(unsigned)(best & 0xFFFFFFFFu);
    }
}

// ---------------- decode winners, histogram (wave-aggregated) --------------
__global__ void decode_kernel(const int* __restrict__ idxs,
                              float* __restrict__ out_idx,
                              int* __restrict__ counts) {
    int i = blockIdx.x * blockDim.x + threadIdx.x;
    if (i >= N_PTS) return;
    int lane = threadIdx.x & 63;
    int idx = idxs[i];
    out_idx[i] = (float)idx;
    int k0 = __shfl(idx, 0);
    unsigned long long same = __ballot(idx == k0);
    if (same == 0xFFFFFFFFFFFFFFFFULL) {
        if (lane == 0) atomicAdd(&counts[idx], 64);
    } else {
        atomicAdd(&counts[idx], 1);
    }
}

// ---------------- quantized = centroids[idx] (one wave per row) ------------
__global__ void quant_kernel(const float* __restrict__ C,
                             const int* __restrict__ idxs,
                             float* __restrict__ outq) {
    int wave = (blockIdx.x * blockDim.x + threadIdx.x) >> 6;
    int lane = threadIdx.x & 63;
    if (wave >= N_PTS) return;
    int idx = idxs[wave];
    const float4* src = (const float4*)(C + (size_t)idx * DIM);
    float4* dst = (float4*)(outq + (size_t)wave * DIM);
    dst[lane] = src[lane];
    dst[lane + 64] = src[lane + 64];
}

// ---------------- exclusive prefix sum of counts (single block) ------------
__global__ __launch_bounds__(1024) void scan_kernel(const int* __restrict__ counts,
                                                    int* __restrict__ offsets) {
    __shared__ int bufA[N_CLU];
    __shared__ int bufB[N_CLU];
    int t = threadIdx.x;
    bufA[t] = counts[t];
    bufA[t + 1024] = counts[t + 1024];
    __syncthreads();
    int* src = bufA;
    int* dst = bufB;
    for (int d = 1; d < N_CLU; d <<= 1) {
        for (int i = t; i < N_CLU; i += 1024) {
            int v = src[i];
            if (i >= d) v += src[i - d];
            dst[i] = v;
        }
        __syncthreads();
        int* tmp = src; src = dst; dst = tmp;
    }
    for (int i = t; i < N_CLU; i += 1024)
        offsets[i] = (i == 0) ? 0 : src[i - 1];
}

// ---------------- bucket placement (counting sort, wave-aggregated) --------
__global__ void place_kernel(const int* __restrict__ idxs,
                             const int* __restrict__ offsets,
                             int* __restrict__ cursor,
                             int* __restrict__ bucket,
                             int* __restrict__ bkey) {
    int i = blockIdx.x * blockDim.x + threadIdx.x;
    if (i >= N_PTS) return;
    int lane = threadIdx.x & 63;
    int k = idxs[i];
    int k0 = __shfl(k, 0);
    unsigned long long same = __ballot(k == k0);
    int pos;
    if (same == 0xFFFFFFFFFFFFFFFFULL) {
        int base = 0;
        if (lane == 0) base = atomicAdd(&cursor[k], 64);
        base = __shfl(base, 0);
        pos = offsets[k] + base + lane;
    } else {
        int r = atomicAdd(&cursor[k], 1);
        pos = offsets[k] + r;
    }
    bucket[pos] = i;
    bkey[pos] = k;
}

// ---------------- new_size (single block) ----------------
__global__ __launch_bounds__(1024) void newsize_kernel(
    const float* __restrict__ ema_size, const int* __restrict__ counts,
    float* __restrict__ out_size) {
    __shared__ float red[16];
    __shared__ float nval;
    int t = threadIdx.x;
    float p0 = ema_size[t] * DECAY + (1.0f - DECAY) * (float)counts[t];
    float p1 = ema_size[t + 1024] * DECAY + (1.0f - DECAY) * (float)counts[t + 1024];
    float s = p0 + p1;
    #pragma unroll
    for (int off = 32; off > 0; off >>= 1) s += __shfl_xor(s, off);
    if ((t & 63) == 0) red[t >> 6] = s;
    __syncthreads();
    if (t == 0) {
        float n = 0.0f;
        for (int i = 0; i < 16; i++) n += red[i];
        nval = n;
    }
    __syncthreads();
    float n = nval;
    float denom = n + (float)N_CLU * EPS;
    out_size[t]        = (p0 + EPS) / denom * n;
    out_size[t + 1024] = (p1 + EPS) / denom * n;
}

// ---------------- dw: chunked segmented reduction over sorted bucket -------
#define CHUNK 64
__global__ __launch_bounds__(256) void dw_kernel(
    const float* __restrict__ X, const int* __restrict__ bucket,
    const int* __restrict__ bkey, float* __restrict__ dw) {
    int c0 = blockIdx.x * CHUNK;
    int t = threadIdx.x;
    float accx = 0.0f, accy = 0.0f;
    int prevk = bkey[c0];
    for (int j = 0; j < CHUNK; j++) {
        int pos = c0 + j;
        int k = bkey[pos];
        if (k != prevk) {
            atomicAdd(&dw[(size_t)prevk * DIM + t * 2 + 0], accx);
            atomicAdd(&dw[(size_t)prevk * DIM + t * 2 + 1], accy);
            accx = 0.0f; accy = 0.0f;
            prevk = k;
        }
        int p = bucket[pos];
        float2 v = *(const float2*)(X + (size_t)p * DIM + t * 2);
        accx += v.x; accy += v.y;
    }
    atomicAdd(&dw[(size_t)prevk * DIM + t * 2 + 0], accx);
    atomicAdd(&dw[(size_t)prevk * DIM + t * 2 + 1], accy);
}

// ---------------- new_w, new_centroids ----------------
__global__ void final_kernel(const float* __restrict__ ema_w,
                             const float* __restrict__ dw,
                             const float* __restrict__ new_size,
                             float* __restrict__ out_neww,
                             float* __restrict__ out_newc) {
    int e = blockIdx.x * blockDim.x + threadIdx.x;
    if (e >= N_CLU * DIM) return;
    int k = e >> 9;
    float nw = ema_w[e] * DECAY + (1.0f - DECAY) * dw[e];
    out_neww[e] = nw;
    out_newc[e] = nw / new_size[k];
}

extern "C" void kernel_launch(void* const* d_in, const int* in_sizes, int n_in,
                              void* d_out, int out_size, void* d_ws, size_t ws_size,
                              hipStream_t stream) {
    const float* X        = (const float*)d_in[0];
    const float* C        = (const float*)d_in[1];
    const float* ema_size = (const float*)d_in[2];
    const float* ema_w    = (const float*)d_in[3];
    float* out = (float*)d_out;

    float* out_q    = out + OUT_Q;
    float* out_idx  = out + OUT_IDX;
    float* out_newc = out + OUT_NEWC;
    float* out_sizep= out + OUT_SIZE;
    float* out_neww = out + OUT_NEWW;

    // Big scratch lives inside out_q's 64 MB region (consumed before
    // quant_kernel overwrites it at the end):
    //   Xh    @ bytes [0, 32M)   — written by prep_x, read by dist_mfma
    //   tile2 @ bytes [32M, 48M) — written by dist_mfma, read by reduce
    _Float16* Xh = (_Float16*)out_q;
    unsigned long long* tile2 =
        (unsigned long long*)((char*)out_q + (size_t)N_PTS * DIM * 2);

    // workspace layout (~7 MB)
    char* ws = (char*)d_ws;
    float* rnorm  = (float*)ws;                                    ws += N_PTS * 4;
    float* cnorm2 = (float*)ws;                                    ws += N_CLU * 4;
    int*   idxs   = (int*)ws;                                      ws += N_PTS * 4;
    int*   counts = (int*)ws;                                      ws += N_CLU * 4;
    int*   offsets= (int*)ws;                                      ws += N_CLU * 4;
    int*   cursor = (int*)ws;                                      ws += N_CLU * 4;
    int*   bucket = (int*)ws;                                      ws += N_PTS * 4;
    int*   bkey   = (int*)ws;                                      ws += N_PTS * 4;
    int*   wl     = (int*)ws;                                      ws += N_PTS * 4;
    int*   wl_cnt = (int*)ws;                                      ws += 16;
    float* dw     = (float*)ws;                                    ws += N_CLU * DIM * 4;
    _Float16* Ch  = (_Float16*)ws;                                 ws += (size_t)N_CLU * DIM * 2;

    init_kernel<<<2048, 256, 0, stream>>>(counts, cursor, wl_cnt, dw);
    prep_x_kernel<<<N_PTS / 4, 256, 0, stream>>>(X, rnorm, Xh);
    prep_c_kernel<<<N_CLU / 4, 256, 0, stream>>>(C, cnorm2, Ch);

    dim3 grid(N_PTS / TBM, N_CLU / TBN);
    dist_mfma_kernel<<<grid, 256, 0, stream>>>(Xh, Ch, cnorm2, tile2);

    reduce_kernel<<<N_PTS / 256, 256, 0, stream>>>(tile2, idxs, wl, wl_cnt);
    exact_kernel<<<256, 256, 0, stream>>>(X, C, rnorm, cnorm2, wl, wl_cnt, idxs);
    decode_kernel<<<N_PTS / 256, 256, 0, stream>>>(idxs, out_idx, counts);
    quant_kernel<<<N_PTS / 4, 256, 0, stream>>>(C, idxs, out_q);
    newsize_kernel<<<1, 1024, 0, stream>>>(ema_size, counts, out_sizep);
    scan_kernel<<<1, 1024, 0, stream>>>(counts, offsets);
    place_kernel<<<N_PTS / 256, 256, 0, stream>>>(idxs, offsets, cursor, bucket, bkey);
    dw_kernel<<<N_PTS / CHUNK, 256, 0, stream>>>(X, bucket, bkey, dw);
    final_kernel<<<(N_CLU * DIM) / 256, 256, 0, stream>>>(ema_w, dw, out_sizep, out_neww, out_newc);
}

// Round 6
// 1033.277 us; speedup vs baseline: 7.4170x; 1.4049x over previous
//
#include <hip/hip_runtime.h>
#include <hip/hip_bf16.h>
#include <stdint.h>

// Problem constants (match reference)
#define N_PTS    32768
#define N_CLU    2048
#define DIM      512
#define DECAY    0.99f
#define EPS      1e-5f
#define NORM_EPS 1e-12f
#define MARGIN   0.02f   // score-gap threshold for exact fp32 re-check (~10 sigma of fp16 error)
#define WCAP     24576   // worklist rows handled by the tiled exact path (48MB of out_q)

// Output layout (flat f32, reference return order)
#define OUT_Q      0
#define OUT_IDX    (N_PTS*DIM)
#define OUT_NEWC   (OUT_IDX + N_PTS)
#define OUT_SIZE   (OUT_NEWC + N_CLU*DIM)
#define OUT_NEWW   (OUT_SIZE + N_CLU)

typedef _Float16 half8 __attribute__((ext_vector_type(8)));
typedef float f32x4 __attribute__((ext_vector_type(4)));

union H8 { _Float16 h[8]; uint4 u; };

// order-preserving f32 -> u32 encode (min-compatible), and decode
__device__ __forceinline__ unsigned enc_f32(float f) {
    unsigned u = __float_as_uint(f);
    return (u & 0x80000000u) ? ~u : (u | 0x80000000u);
}
__device__ __forceinline__ float dec_f32(unsigned e) {
    unsigned u = (e & 0x80000000u) ? (e & 0x7FFFFFFFu) : ~e;
    return __uint_as_float(u);
}

// ---------------- init workspace ----------------
__global__ void init_kernel(int* __restrict__ counts,
                            int* __restrict__ cursor,
                            int* __restrict__ wl_cnt,
                            float* __restrict__ dw,
                            unsigned long long* __restrict__ best64) {
    int i = blockIdx.x * blockDim.x + threadIdx.x;
    int stride = gridDim.x * blockDim.x;
    if (i == 0) wl_cnt[0] = 0;
    for (int j = i; j < N_CLU; j += stride) { counts[j] = 0; cursor[j] = 0; }
    for (int j = i; j < N_CLU * DIM; j += stride) dw[j] = 0.0f;
    for (int j = i; j < WCAP; j += stride) best64[j] = 0xFFFFFFFFFFFFFFFFULL;
}

// ---------------- rnorm + normalized X in fp16 (one wave per row) ----------
__global__ void prep_x_kernel(const float* __restrict__ X,
                              float* __restrict__ rnorm,
                              _Float16* __restrict__ Xh) {
    int row = (blockIdx.x * blockDim.x + threadIdx.x) >> 6;
    int lane = threadIdx.x & 63;
    if (row >= N_PTS) return;
    const float4* xr = (const float4*)(X + (size_t)row * DIM);
    float4 a = xr[2 * lane];
    float4 b = xr[2 * lane + 1];
    float ss = a.x*a.x + a.y*a.y + a.z*a.z + a.w*a.w
             + b.x*b.x + b.y*b.y + b.z*b.z + b.w*b.w;
    #pragma unroll
    for (int off = 32; off > 0; off >>= 1) ss += __shfl_xor(ss, off);
    float rs = 1.0f / fmaxf(sqrtf(ss), NORM_EPS);
    if (lane == 0) rnorm[row] = rs;
    H8 o;
    o.h[0] = (_Float16)(a.x * rs); o.h[1] = (_Float16)(a.y * rs);
    o.h[2] = (_Float16)(a.z * rs); o.h[3] = (_Float16)(a.w * rs);
    o.h[4] = (_Float16)(b.x * rs); o.h[5] = (_Float16)(b.y * rs);
    o.h[6] = (_Float16)(b.z * rs); o.h[7] = (_Float16)(b.w * rs);
    *(uint4*)(Xh + (size_t)row * DIM + lane * 8) = o.u;
}

// ---------------- |c|^2 + C in fp16 (one wave per centroid) ----------------
__global__ void prep_c_kernel(const float* __restrict__ C,
                              float* __restrict__ cnorm2,
                              _Float16* __restrict__ Ch) {
    int row = (blockIdx.x * blockDim.x + threadIdx.x) >> 6;
    int lane = threadIdx.x & 63;
    if (row >= N_CLU) return;
    const float4* cr = (const float4*)(C + (size_t)row * DIM);
    float4 a = cr[2 * lane];
    float4 b = cr[2 * lane + 1];
    float ss = a.x*a.x + a.y*a.y + a.z*a.z + a.w*a.w
             + b.x*b.x + b.y*b.y + b.z*b.z + b.w*b.w;
    #pragma unroll
    for (int off = 32; off > 0; off >>= 1) ss += __shfl_xor(ss, off);
    if (lane == 0) cnorm2[row] = ss;
    H8 o;
    o.h[0] = (_Float16)a.x; o.h[1] = (_Float16)a.y;
    o.h[2] = (_Float16)a.z; o.h[3] = (_Float16)a.w;
    o.h[4] = (_Float16)b.x; o.h[5] = (_Float16)b.y;
    o.h[6] = (_Float16)b.z; o.h[7] = (_Float16)b.w;
    *(uint4*)(Ch + (size_t)row * DIM + lane * 8) = o.u;
}

// ---------------- MFMA fp16 GEMM + per-row per-(tile,wc) top-2 -------------
// 128x128 tile, BK=32, 4 waves in (wr,wc) 64x64 quadrants, 4x4 frags of
// 16x16x32. LDS rows padded to 40 halves (80B, 16B-aligned): row-starts
// (row*20)%32 hit 8 distinct bank-quads -> frag ds_read_b128 spreads all 32
// banks uniformly (structural-minimum 2 slots/bank = free, m136).
#define TBM 128
#define TBN 128
#define TBK 32
#define LDS_S 40

__global__ __launch_bounds__(256) void dist_mfma_kernel(
    const _Float16* __restrict__ Xh, const _Float16* __restrict__ Ch,
    const float* __restrict__ cnorm2,
    unsigned long long* __restrict__ tile2) {
    __shared__ _Float16 Ah[TBM * LDS_S];
    __shared__ _Float16 Bh[TBN * LDS_S];

    const int tid = threadIdx.x;
    const int m0 = blockIdx.x * TBM;
    const int n0 = blockIdx.y * TBN;

    const int wid = tid >> 6;
    const int l = tid & 63;
    const int wr = wid >> 1, wc = wid & 1;
    const int lr = l & 15, g = l >> 4;

    // staging: thread t handles row=t>>1, khalf=t&1 (16 halves = 32B)
    const int srow = tid >> 1, shalf = tid & 1;
    const _Float16* srcA = Xh + (size_t)(m0 + srow) * DIM + shalf * 16;
    const _Float16* srcB = Ch + (size_t)(n0 + srow) * DIM + shalf * 16;
    _Float16* dstA = &Ah[srow * LDS_S + shalf * 16];
    _Float16* dstB = &Bh[srow * LDS_S + shalf * 16];

    f32x4 acc[4][4];
    #pragma unroll
    for (int m = 0; m < 4; m++)
        #pragma unroll
        for (int n = 0; n < 4; n++) acc[m][n] = (f32x4){0.f, 0.f, 0.f, 0.f};

    for (int k0 = 0; k0 < DIM; k0 += TBK) {
        const uint4* pa = (const uint4*)(srcA + k0);
        const uint4* pb = (const uint4*)(srcB + k0);
        uint4 a0 = pa[0], a1 = pa[1];
        uint4 b0 = pb[0], b1 = pb[1];
        *(uint4*)dstA = a0; *(uint4*)(dstA + 8) = a1;
        *(uint4*)dstB = b0; *(uint4*)(dstB + 8) = b1;
        __syncthreads();

        half8 af[4], bf[4];
        #pragma unroll
        for (int m = 0; m < 4; m++)
            af[m] = *(const half8*)&Ah[(wr * 64 + m * 16 + lr) * LDS_S + g * 8];
        #pragma unroll
        for (int n = 0; n < 4; n++)
            bf[n] = *(const half8*)&Bh[(wc * 64 + n * 16 + lr) * LDS_S + g * 8];
        #pragma unroll
        for (int m = 0; m < 4; m++)
            #pragma unroll
            for (int n = 0; n < 4; n++)
                acc[m][n] = __builtin_amdgcn_mfma_f32_16x16x32_f16(af[m], bf[n], acc[m][n], 0, 0, 0);
        __syncthreads();
    }

    // epilogue: per-row top-2 across this wave's 64 columns
    float cn2[4];
    int coln[4];
    #pragma unroll
    for (int n = 0; n < 4; n++) {
        coln[n] = n0 + wc * 64 + n * 16 + lr;
        cn2[n] = cnorm2[coln[n]];
    }
    const int slot = blockIdx.y * 2 + wc;
    #pragma unroll
    for (int m = 0; m < 4; m++) {
        #pragma unroll
        for (int reg = 0; reg < 4; reg++) {
            unsigned long long b1 = ~0ULL, b2 = ~0ULL;
            #pragma unroll
            for (int n = 0; n < 4; n++) {
                float s = cn2[n] - 2.0f * acc[m][n][reg];
                unsigned long long p =
                    ((unsigned long long)enc_f32(s) << 32) | (unsigned)coln[n];
                if (p < b1) { b2 = b1; b1 = p; }
                else if (p < b2) { b2 = p; }
            }
            #pragma unroll
            for (int off = 1; off < 16; off <<= 1) {
                unsigned long long c1 = __shfl_xor(b1, off);
                unsigned long long c2 = __shfl_xor(b2, off);
                if (c1 < b1) { b2 = (b1 < c2) ? b1 : c2; b1 = c1; }
                else         { b2 = (b2 < c1) ? b2 : c1; }
            }
            if (lr == 0) {
                int R = m0 + wr * 64 + m * 16 + g * 4 + reg;
                size_t o = ((size_t)slot * N_PTS + R) * 2;
                tile2[o] = b1;
                tile2[o + 1] = b2;
            }
        }
    }
}

// ---------------- global top-2 reduce + margin flag ----------------
__global__ void reduce_kernel(const unsigned long long* __restrict__ tile2,
                              int* __restrict__ idxs,
                              int* __restrict__ wl, int* __restrict__ wl_cnt) {
    int i = blockIdx.x * blockDim.x + threadIdx.x;
    if (i >= N_PTS) return;
    unsigned long long b1 = ~0ULL, b2 = ~0ULL;
    #pragma unroll
    for (int j = 0; j < 32; j++) {
        size_t o = ((size_t)j * N_PTS + i) * 2;
        unsigned long long c1 = tile2[o], c2 = tile2[o + 1];
        if (c1 < b1) { b2 = (b1 < c2) ? b1 : c2; b1 = c1; }
        else         { b2 = (b2 < c1) ? b2 : c1; }
    }
    idxs[i] = (int)(unsigned)(b1 & 0xFFFFFFFFu);
    float gap = dec_f32((unsigned)(b2 >> 32)) - dec_f32((unsigned)(b1 >> 32));
    if (gap < MARGIN) {
        int pos = atomicAdd(wl_cnt, 1);
        wl[pos] = i;
    }
}

// ---------------- gather normalized fp32 rows for flagged points -----------
__global__ void gather_kernel(const float* __restrict__ X,
                              const float* __restrict__ rnorm,
                              const int* __restrict__ wl,
                              const int* __restrict__ wl_cnt,
                              float* __restrict__ Xg) {
    int gw = (blockIdx.x * blockDim.x + threadIdx.x) >> 6;
    int lane = threadIdx.x & 63;
    int n = wl_cnt[0];
    if (n > WCAP) n = WCAP;
    for (int pos = gw; pos < n; pos += 2048) {
        int i = wl[pos];
        float rs = rnorm[i];
        const float4* src = (const float4*)(X + (size_t)i * DIM);
        float4* dst = (float4*)(Xg + (size_t)pos * DIM);
        float4 a = src[2 * lane], b = src[2 * lane + 1];
        a.x *= rs; a.y *= rs; a.z *= rs; a.w *= rs;
        b.x *= rs; b.y *= rs; b.z *= rs; b.w *= rs;
        dst[2 * lane] = a;
        dst[2 * lane + 1] = b;
    }
}

// ---------------- tiled fp32 GEMM + argmin over the worklist ----------------
// R3-proven structure: 128x128 tile, BK=16, 8x8 microtile, atomicMin combine.
#define BM 128
#define BN 128
#define BK 16

__global__ __launch_bounds__(256) void exact_tile_kernel(
    const float* __restrict__ Xg, const float* __restrict__ C,
    const float* __restrict__ cnorm2, const int* __restrict__ wl_cnt,
    unsigned long long* __restrict__ best64) {
    const int m0 = blockIdx.x * BM;
    int n = wl_cnt[0];
    if (n > WCAP) n = WCAP;
    if (m0 >= n) return;

    __shared__ float As[BK][BM];   // K-major
    __shared__ float Bs[BK][BN];

    const int tid = threadIdx.x;
    const int tx = tid & 15;
    const int ty = tid >> 4;
    const int n0 = blockIdx.y * BN;

    const int f0 = tid;
    const int f1 = tid + 256;
    const int rowA0 = f0 >> 2, kq0 = f0 & 3;
    const int rowA1 = f1 >> 2, kq1 = f1 & 3;
    const float* Abase0 = Xg + (size_t)(m0 + rowA0) * DIM + kq0 * 4;
    const float* Abase1 = Xg + (size_t)(m0 + rowA1) * DIM + kq1 * 4;
    const float* Bbase0 = C + (size_t)(n0 + rowA0) * DIM + kq0 * 4;
    const float* Bbase1 = C + (size_t)(n0 + rowA1) * DIM + kq1 * 4;

    float acc[8][8];
    #pragma unroll
    for (int r = 0; r < 8; r++)
        #pragma unroll
        for (int c = 0; c < 8; c++) acc[r][c] = 0.0f;

    for (int c0 = 0; c0 < DIM; c0 += BK) {
        float4 va0 = *(const float4*)(Abase0 + c0);
        float4 va1 = *(const float4*)(Abase1 + c0);
        float4 vb0 = *(const float4*)(Bbase0 + c0);
        float4 vb1 = *(const float4*)(Bbase1 + c0);
        As[kq0*4+0][rowA0] = va0.x; As[kq0*4+1][rowA0] = va0.y;
        As[kq0*4+2][rowA0] = va0.z; As[kq0*4+3][rowA0] = va0.w;
        As[kq1*4+0][rowA1] = va1.x; As[kq1*4+1][rowA1] = va1.y;
        As[kq1*4+2][rowA1] = va1.z; As[kq1*4+3][rowA1] = va1.w;
        Bs[kq0*4+0][rowA0] = vb0.x; Bs[kq0*4+1][rowA0] = vb0.y;
        Bs[kq0*4+2][rowA0] = vb0.z; Bs[kq0*4+3][rowA0] = vb0.w;
        Bs[kq1*4+0][rowA1] = vb1.x; Bs[kq1*4+1][rowA1] = vb1.y;
        Bs[kq1*4+2][rowA1] = vb1.z; Bs[kq1*4+3][rowA1] = vb1.w;
        __syncthreads();

        #pragma unroll
        for (int t = 0; t < BK; t++) {
            float4 a0 = *(const float4*)&As[t][ty * 8];
            float4 a1 = *(const float4*)&As[t][ty * 8 + 4];
            float4 b0 = *(const float4*)&Bs[t][tx * 8];
            float4 b1 = *(const float4*)&Bs[t][tx * 8 + 4];
            float a[8] = {a0.x, a0.y, a0.z, a0.w, a1.x, a1.y, a1.z, a1.w};
            float b[8] = {b0.x, b0.y, b0.z, b0.w, b1.x, b1.y, b1.z, b1.w};
            #pragma unroll
            for (int r = 0; r < 8; r++)
                #pragma unroll
                for (int c = 0; c < 8; c++)
                    acc[r][c] = fmaf(a[r], b[c], acc[r][c]);
        }
        __syncthreads();
    }

    #pragma unroll
    for (int r = 0; r < 8; r++) {
        float bs = INFINITY;
        int bi = 0x7FFFFFFF;
        #pragma unroll
        for (int c = 0; c < 8; c++) {
            int gc = n0 + tx * 8 + c;
            float s = cnorm2[gc] - 2.0f * acc[r][c];
            if (s < bs) { bs = s; bi = gc; }
        }
        unsigned long long p =
            ((unsigned long long)enc_f32(bs) << 32) | (unsigned)bi;
        #pragma unroll
        for (int off = 1; off < 16; off <<= 1) {
            unsigned long long q = __shfl_xor(p, off);
            if (q < p) p = q;
        }
        if (tx == 0) atomicMin(best64 + m0 + ty * 8 + r, p);
    }
}

// ---------------- write tiled-exact winners back to idxs -------------------
__global__ void writeback_kernel(const unsigned long long* __restrict__ best64,
                                 const int* __restrict__ wl,
                                 const int* __restrict__ wl_cnt,
                                 int* __restrict__ idxs) {
    int pos = blockIdx.x * blockDim.x + threadIdx.x;
    int n = wl_cnt[0];
    if (n > WCAP) n = WCAP;
    if (pos >= n) return;
    idxs[wl[pos]] = (int)(unsigned)(best64[pos] & 0xFFFFFFFFu);
}

// ---------------- serial exact fallback (worklist overflow only) -----------
__global__ __launch_bounds__(256) void exact_serial_kernel(
    const float* __restrict__ X, const float* __restrict__ C,
    const float* __restrict__ rnorm, const float* __restrict__ cnorm2,
    const int* __restrict__ wl, const int* __restrict__ wl_cnt,
    int* __restrict__ idxs) {
    int gw = (blockIdx.x * blockDim.x + threadIdx.x) >> 6;
    int lane = threadIdx.x & 63;
    int n = wl_cnt[0];
    for (int it = WCAP + gw; it < n; it += 1024) {
        int i = wl[it];
        float rs = rnorm[i];
        const float4* xr = (const float4*)(X + (size_t)i * DIM);
        float4 xa = xr[2 * lane], xb = xr[2 * lane + 1];
        xa.x *= rs; xa.y *= rs; xa.z *= rs; xa.w *= rs;
        xb.x *= rs; xb.y *= rs; xb.z *= rs; xb.w *= rs;
        unsigned long long best = ~0ULL;
        for (int k = 0; k < N_CLU; k++) {
            const float4* cr = (const float4*)(C + (size_t)k * DIM);
            float4 ca = cr[2 * lane], cb = cr[2 * lane + 1];
            float d = xa.x*ca.x + xa.y*ca.y + xa.z*ca.z + xa.w*ca.w
                    + xb.x*cb.x + xb.y*cb.y + xb.z*cb.z + xb.w*cb.w;
            #pragma unroll
            for (int off = 32; off > 0; off >>= 1) d += __shfl_xor(d, off);
            float s = cnorm2[k] - 2.0f * d;
            unsigned long long p =
                ((unsigned long long)enc_f32(s) << 32) | (unsigned)k;
            if (p < best) best = p;
        }
        if (lane == 0) idxs[i] = (int)(unsigned)(best & 0xFFFFFFFFu);
    }
}

// ---------------- decode winners, histogram (wave-aggregated) --------------
__global__ void decode_kernel(const int* __restrict__ idxs,
                              float* __restrict__ out_idx,
                              int* __restrict__ counts) {
    int i = blockIdx.x * blockDim.x + threadIdx.x;
    if (i >= N_PTS) return;
    int lane = threadIdx.x & 63;
    int idx = idxs[i];
    out_idx[i] = (float)idx;
    int k0 = __shfl(idx, 0);
    unsigned long long same = __ballot(idx == k0);
    if (same == 0xFFFFFFFFFFFFFFFFULL) {
        if (lane == 0) atomicAdd(&counts[idx], 64);
    } else {
        atomicAdd(&counts[idx], 1);
    }
}

// ---------------- quantized = centroids[idx] (one wave per row) ------------
__global__ void quant_kernel(const float* __restrict__ C,
                             const int* __restrict__ idxs,
                             float* __restrict__ outq) {
    int wave = (blockIdx.x * blockDim.x + threadIdx.x) >> 6;
    int lane = threadIdx.x & 63;
    if (wave >= N_PTS) return;
    int idx = idxs[wave];
    const float4* src = (const float4*)(C + (size_t)idx * DIM);
    float4* dst = (float4*)(outq + (size_t)wave * DIM);
    dst[lane] = src[lane];
    dst[lane + 64] = src[lane + 64];
}

// ---------------- exclusive prefix sum of counts (single block) ------------
__global__ __launch_bounds__(1024) void scan_kernel(const int* __restrict__ counts,
                                                    int* __restrict__ offsets) {
    __shared__ int bufA[N_CLU];
    __shared__ int bufB[N_CLU];
    int t = threadIdx.x;
    bufA[t] = counts[t];
    bufA[t + 1024] = counts[t + 1024];
    __syncthreads();
    int* src = bufA;
    int* dst = bufB;
    for (int d = 1; d < N_CLU; d <<= 1) {
        for (int i = t; i < N_CLU; i += 1024) {
            int v = src[i];
            if (i >= d) v += src[i - d];
            dst[i] = v;
        }
        __syncthreads();
        int* tmp = src; src = dst; dst = tmp;
    }
    for (int i = t; i < N_CLU; i += 1024)
        offsets[i] = (i == 0) ? 0 : src[i - 1];
}

// ---------------- bucket placement (counting sort, wave-aggregated) --------
__global__ void place_kernel(const int* __restrict__ idxs,
                             const int* __restrict__ offsets,
                             int* __restrict__ cursor,
                             int* __restrict__ bucket,
                             int* __restrict__ bkey) {
    int i = blockIdx.x * blockDim.x + threadIdx.x;
    if (i >= N_PTS) return;
    int lane = threadIdx.x & 63;
    int k = idxs[i];
    int k0 = __shfl(k, 0);
    unsigned long long same = __ballot(k == k0);
    int pos;
    if (same == 0xFFFFFFFFFFFFFFFFULL) {
        int base = 0;
        if (lane == 0) base = atomicAdd(&cursor[k], 64);
        base = __shfl(base, 0);
        pos = offsets[k] + base + lane;
    } else {
        int r = atomicAdd(&cursor[k], 1);
        pos = offsets[k] + r;
    }
    bucket[pos] = i;
    bkey[pos] = k;
}

// ---------------- new_size (single block) ----------------
__global__ __launch_bounds__(1024) void newsize_kernel(
    const float* __restrict__ ema_size, const int* __restrict__ counts,
    float* __restrict__ out_size) {
    __shared__ float red[16];
    __shared__ float nval;
    int t = threadIdx.x;
    float p0 = ema_size[t] * DECAY + (1.0f - DECAY) * (float)counts[t];
    float p1 = ema_size[t + 1024] * DECAY + (1.0f - DECAY) * (float)counts[t + 1024];
    float s = p0 + p1;
    #pragma unroll
    for (int off = 32; off > 0; off >>= 1) s += __shfl_xor(s, off);
    if ((t & 63) == 0) red[t >> 6] = s;
    __syncthreads();
    if (t == 0) {
        float n = 0.0f;
        for (int i = 0; i < 16; i++) n += red[i];
        nval = n;
    }
    __syncthreads();
    float n = nval;
    float denom = n + (float)N_CLU * EPS;
    out_size[t]        = (p0 + EPS) / denom * n;
    out_size[t + 1024] = (p1 + EPS) / denom * n;
}

// ---------------- dw: chunked segmented reduction over sorted bucket -------
#define CHUNK 64
__global__ __launch_bounds__(256) void dw_kernel(
    const float* __restrict__ X, const int* __restrict__ bucket,
    const int* __restrict__ bkey, float* __restrict__ dw) {
    int c0 = blockIdx.x * CHUNK;
    int t = threadIdx.x;
    float accx = 0.0f, accy = 0.0f;
    int prevk = bkey[c0];
    for (int j = 0; j < CHUNK; j++) {
        int pos = c0 + j;
        int k = bkey[pos];
        if (k != prevk) {
            atomicAdd(&dw[(size_t)prevk * DIM + t * 2 + 0], accx);
            atomicAdd(&dw[(size_t)prevk * DIM + t * 2 + 1], accy);
            accx = 0.0f; accy = 0.0f;
            prevk = k;
        }
        int p = bucket[pos];
        float2 v = *(const float2*)(X + (size_t)p * DIM + t * 2);
        accx += v.x; accy += v.y;
    }
    atomicAdd(&dw[(size_t)prevk * DIM + t * 2 + 0], accx);
    atomicAdd(&dw[(size_t)prevk * DIM + t * 2 + 1], accy);
}

// ---------------- new_w, new_centroids ----------------
__global__ void final_kernel(const float* __restrict__ ema_w,
                             const float* __restrict__ dw,
                             const float* __restrict__ new_size,
                             float* __restrict__ out_neww,
                             float* __restrict__ out_newc) {
    int e = blockIdx.x * blockDim.x + threadIdx.x;
    if (e >= N_CLU * DIM) return;
    int k = e >> 9;
    float nw = ema_w[e] * DECAY + (1.0f - DECAY) * dw[e];
    out_neww[e] = nw;
    out_newc[e] = nw / new_size[k];
}

extern "C" void kernel_launch(void* const* d_in, const int* in_sizes, int n_in,
                              void* d_out, int out_size, void* d_ws, size_t ws_size,
                              hipStream_t stream) {
    const float* X        = (const float*)d_in[0];
    const float* C        = (const float*)d_in[1];
    const float* ema_size = (const float*)d_in[2];
    const float* ema_w    = (const float*)d_in[3];
    float* out = (float*)d_out;

    float* out_q    = out + OUT_Q;
    float* out_idx  = out + OUT_IDX;
    float* out_newc = out + OUT_NEWC;
    float* out_sizep= out + OUT_SIZE;
    float* out_neww = out + OUT_NEWW;

    // Big scratch lives inside out_q's 64 MB region, consumed before
    // quant_kernel overwrites it at the end:
    //   Xh    @ [0, 32M)   — prep_x -> dist_mfma
    //   tile2 @ [32M, 48M) — dist_mfma -> reduce
    //   Xg    @ [0, 48M)   — gather -> exact_tile (Xh/tile2 dead by then)
    _Float16* Xh = (_Float16*)out_q;
    unsigned long long* tile2 =
        (unsigned long long*)((char*)out_q + (size_t)N_PTS * DIM * 2);
    float* Xg = (float*)out_q;

    // workspace layout (~7.4 MB)
    char* ws = (char*)d_ws;
    float* rnorm  = (float*)ws;                                    ws += N_PTS * 4;
    float* cnorm2 = (float*)ws;                                    ws += N_CLU * 4;
    int*   idxs   = (int*)ws;                                      ws += N_PTS * 4;
    int*   counts = (int*)ws;                                      ws += N_CLU * 4;
    int*   offsets= (int*)ws;                                      ws += N_CLU * 4;
    int*   cursor = (int*)ws;                                      ws += N_CLU * 4;
    int*   bucket = (int*)ws;                                      ws += N_PTS * 4;
    int*   bkey   = (int*)ws;                                      ws += N_PTS * 4;
    int*   wl     = (int*)ws;                                      ws += N_PTS * 4;
    int*   wl_cnt = (int*)ws;                                      ws += 16;
    float* dw     = (float*)ws;                                    ws += N_CLU * DIM * 4;
    _Float16* Ch  = (_Float16*)ws;                                 ws += (size_t)N_CLU * DIM * 2;
    unsigned long long* best64 = (unsigned long long*)ws;          ws += (size_t)WCAP * 8;

    init_kernel<<<2048, 256, 0, stream>>>(counts, cursor, wl_cnt, dw, best64);
    prep_x_kernel<<<N_PTS / 4, 256, 0, stream>>>(X, rnorm, Xh);
    prep_c_kernel<<<N_CLU / 4, 256, 0, stream>>>(C, cnorm2, Ch);

    dim3 grid(N_PTS / TBM, N_CLU / TBN);
    dist_mfma_kernel<<<grid, 256, 0, stream>>>(Xh, Ch, cnorm2, tile2);

    reduce_kernel<<<N_PTS / 256, 256, 0, stream>>>(tile2, idxs, wl, wl_cnt);
    gather_kernel<<<512, 256, 0, stream>>>(X, rnorm, wl, wl_cnt, Xg);
    dim3 egrid(WCAP / BM, N_CLU / BN);
    exact_tile_kernel<<<egrid, 256, 0, stream>>>(Xg, C, cnorm2, wl_cnt, best64);
    writeback_kernel<<<WCAP / 256, 256, 0, stream>>>(best64, wl, wl_cnt, idxs);
    exact_serial_kernel<<<256, 256, 0, stream>>>(X, C, rnorm, cnorm2, wl, wl_cnt, idxs);

    decode_kernel<<<N_PTS / 256, 256, 0, stream>>>(idxs, out_idx, counts);
    quant_kernel<<<N_PTS / 4, 256, 0, stream>>>(C, idxs, out_q);
    newsize_kernel<<<1, 1024, 0, stream>>>(ema_size, counts, out_sizep);
    scan_kernel<<<1, 1024, 0, stream>>>(counts, offsets);
    place_kernel<<<N_PTS / 256, 256, 0, stream>>>(idxs, offsets, cursor, bucket, bkey);
    dw_kernel<<<N_PTS / CHUNK, 256, 0, stream>>>(X, bucket, bkey, dw);
    final_kernel<<<(N_CLU * DIM) / 256, 256, 0, stream>>>(ema_w, dw, out_sizep, out_neww, out_newc);
}

// Round 7
// 513.660 us; speedup vs baseline: 14.9199x; 2.0116x over previous
//
#include <hip/hip_runtime.h>
#include <hip/hip_bf16.h>
#include <stdint.h>

// Problem constants (match reference)
#define N_PTS    32768
#define N_CLU    2048
#define DIM      512
#define DECAY    0.99f
#define EPS      1e-5f
#define NORM_EPS 1e-12f
#define MARGIN   0.02f   // score-gap threshold for exact fp32 re-check (~10 sigma of fp16 error)
#define WCAP     24576   // worklist rows handled by the tiled exact path (48MB of out_q)

// Output layout (flat f32, reference return order)
#define OUT_Q      0
#define OUT_IDX    (N_PTS*DIM)
#define OUT_NEWC   (OUT_IDX + N_PTS)
#define OUT_SIZE   (OUT_NEWC + N_CLU*DIM)
#define OUT_NEWW   (OUT_SIZE + N_CLU)

typedef _Float16 half8 __attribute__((ext_vector_type(8)));
typedef float f32x4 __attribute__((ext_vector_type(4)));

union H8 { _Float16 h[8]; uint4 u; };

// order-preserving f32 -> u32 encode (min-compatible), and decode
__device__ __forceinline__ unsigned enc_f32(float f) {
    unsigned u = __float_as_uint(f);
    return (u & 0x80000000u) ? ~u : (u | 0x80000000u);
}
__device__ __forceinline__ float dec_f32(unsigned e) {
    unsigned u = (e & 0x80000000u) ? (e & 0x7FFFFFFFu) : ~e;
    return __uint_as_float(u);
}

// ---------------- init workspace ----------------
__global__ void init_kernel(int* __restrict__ counts,
                            int* __restrict__ cursor,
                            int* __restrict__ wl_cnt,
                            float* __restrict__ dw,
                            unsigned long long* __restrict__ best64) {
    int i = blockIdx.x * blockDim.x + threadIdx.x;
    int stride = gridDim.x * blockDim.x;
    if (i == 0) wl_cnt[0] = 0;
    for (int j = i; j < N_CLU; j += stride) { counts[j] = 0; cursor[j] = 0; }
    for (int j = i; j < N_CLU * DIM; j += stride) dw[j] = 0.0f;
    for (int j = i; j < WCAP; j += stride) best64[j] = 0xFFFFFFFFFFFFFFFFULL;
}

// ---------------- rnorm + normalized X in fp16 (one wave per row) ----------
__global__ void prep_x_kernel(const float* __restrict__ X,
                              float* __restrict__ rnorm,
                              _Float16* __restrict__ Xh) {
    int row = (blockIdx.x * blockDim.x + threadIdx.x) >> 6;
    int lane = threadIdx.x & 63;
    if (row >= N_PTS) return;
    const float4* xr = (const float4*)(X + (size_t)row * DIM);
    float4 a = xr[2 * lane];
    float4 b = xr[2 * lane + 1];
    float ss = a.x*a.x + a.y*a.y + a.z*a.z + a.w*a.w
             + b.x*b.x + b.y*b.y + b.z*b.z + b.w*b.w;
    #pragma unroll
    for (int off = 32; off > 0; off >>= 1) ss += __shfl_xor(ss, off);
    float rs = 1.0f / fmaxf(sqrtf(ss), NORM_EPS);
    if (lane == 0) rnorm[row] = rs;
    H8 o;
    o.h[0] = (_Float16)(a.x * rs); o.h[1] = (_Float16)(a.y * rs);
    o.h[2] = (_Float16)(a.z * rs); o.h[3] = (_Float16)(a.w * rs);
    o.h[4] = (_Float16)(b.x * rs); o.h[5] = (_Float16)(b.y * rs);
    o.h[6] = (_Float16)(b.z * rs); o.h[7] = (_Float16)(b.w * rs);
    *(uint4*)(Xh + (size_t)row * DIM + lane * 8) = o.u;
}

// ---------------- |c|^2 + C in fp16 (one wave per centroid) ----------------
__global__ void prep_c_kernel(const float* __restrict__ C,
                              float* __restrict__ cnorm2,
                              _Float16* __restrict__ Ch) {
    int row = (blockIdx.x * blockDim.x + threadIdx.x) >> 6;
    int lane = threadIdx.x & 63;
    if (row >= N_CLU) return;
    const float4* cr = (const float4*)(C + (size_t)row * DIM);
    float4 a = cr[2 * lane];
    float4 b = cr[2 * lane + 1];
    float ss = a.x*a.x + a.y*a.y + a.z*a.z + a.w*a.w
             + b.x*b.x + b.y*b.y + b.z*b.z + b.w*b.w;
    #pragma unroll
    for (int off = 32; off > 0; off >>= 1) ss += __shfl_xor(ss, off);
    if (lane == 0) cnorm2[row] = ss;
    H8 o;
    o.h[0] = (_Float16)a.x; o.h[1] = (_Float16)a.y;
    o.h[2] = (_Float16)a.z; o.h[3] = (_Float16)a.w;
    o.h[4] = (_Float16)b.x; o.h[5] = (_Float16)b.y;
    o.h[6] = (_Float16)b.z; o.h[7] = (_Float16)b.w;
    *(uint4*)(Ch + (size_t)row * DIM + lane * 8) = o.u;
}

// ---------------- MFMA fp16 GEMM + per-row per-(tile,wc) top-2 -------------
// 128x128 tile, BK=32, 4 waves in (wr,wc) 64x64 quadrants, 4x4 frags of
// 16x16x32. LDS rows padded to 40 halves (80B, 16B-aligned): row-starts
// (row*20)%32 hit 8 distinct bank-quads -> frag ds_read_b128 spreads all 32
// banks uniformly (structural-minimum 2 slots/bank = free, m136).
#define TBM 128
#define TBN 128
#define TBK 32
#define LDS_S 40

__global__ __launch_bounds__(256) void dist_mfma_kernel(
    const _Float16* __restrict__ Xh, const _Float16* __restrict__ Ch,
    const float* __restrict__ cnorm2,
    unsigned long long* __restrict__ tile2) {
    __shared__ _Float16 Ah[TBM * LDS_S];
    __shared__ _Float16 Bh[TBN * LDS_S];

    const int tid = threadIdx.x;
    const int m0 = blockIdx.x * TBM;
    const int n0 = blockIdx.y * TBN;

    const int wid = tid >> 6;
    const int l = tid & 63;
    const int wr = wid >> 1, wc = wid & 1;
    const int lr = l & 15, g = l >> 4;

    // staging: thread t handles row=t>>1, khalf=t&1 (16 halves = 32B)
    const int srow = tid >> 1, shalf = tid & 1;
    const _Float16* srcA = Xh + (size_t)(m0 + srow) * DIM + shalf * 16;
    const _Float16* srcB = Ch + (size_t)(n0 + srow) * DIM + shalf * 16;
    _Float16* dstA = &Ah[srow * LDS_S + shalf * 16];
    _Float16* dstB = &Bh[srow * LDS_S + shalf * 16];

    f32x4 acc[4][4];
    #pragma unroll
    for (int m = 0; m < 4; m++)
        #pragma unroll
        for (int n = 0; n < 4; n++) acc[m][n] = (f32x4){0.f, 0.f, 0.f, 0.f};

    for (int k0 = 0; k0 < DIM; k0 += TBK) {
        const uint4* pa = (const uint4*)(srcA + k0);
        const uint4* pb = (const uint4*)(srcB + k0);
        uint4 a0 = pa[0], a1 = pa[1];
        uint4 b0 = pb[0], b1 = pb[1];
        *(uint4*)dstA = a0; *(uint4*)(dstA + 8) = a1;
        *(uint4*)dstB = b0; *(uint4*)(dstB + 8) = b1;
        __syncthreads();

        half8 af[4], bf[4];
        #pragma unroll
        for (int m = 0; m < 4; m++)
            af[m] = *(const half8*)&Ah[(wr * 64 + m * 16 + lr) * LDS_S + g * 8];
        #pragma unroll
        for (int n = 0; n < 4; n++)
            bf[n] = *(const half8*)&Bh[(wc * 64 + n * 16 + lr) * LDS_S + g * 8];
        #pragma unroll
        for (int m = 0; m < 4; m++)
            #pragma unroll
            for (int n = 0; n < 4; n++)
                acc[m][n] = __builtin_amdgcn_mfma_f32_16x16x32_f16(af[m], bf[n], acc[m][n], 0, 0, 0);
        __syncthreads();
    }

    // epilogue: per-row top-2 across this wave's 64 columns
    float cn2[4];
    int coln[4];
    #pragma unroll
    for (int n = 0; n < 4; n++) {
        coln[n] = n0 + wc * 64 + n * 16 + lr;
        cn2[n] = cnorm2[coln[n]];
    }
    const int slot = blockIdx.y * 2 + wc;
    #pragma unroll
    for (int m = 0; m < 4; m++) {
        #pragma unroll
        for (int reg = 0; reg < 4; reg++) {
            unsigned long long b1 = ~0ULL, b2 = ~0ULL;
            #pragma unroll
            for (int n = 0; n < 4; n++) {
                float s = cn2[n] - 2.0f * acc[m][n][reg];
                unsigned long long p =
                    ((unsigned long long)enc_f32(s) << 32) | (unsigned)coln[n];
                if (p < b1) { b2 = b1; b1 = p; }
                else if (p < b2) { b2 = p; }
            }
            #pragma unroll
            for (int off = 1; off < 16; off <<= 1) {
                unsigned long long c1 = __shfl_xor(b1, off);
                unsigned long long c2 = __shfl_xor(b2, off);
                if (c1 < b1) { b2 = (b1 < c2) ? b1 : c2; b1 = c1; }
                else         { b2 = (b2 < c1) ? b2 : c1; }
            }
            if (lr == 0) {
                int R = m0 + wr * 64 + m * 16 + g * 4 + reg;
                size_t o = ((size_t)slot * N_PTS + R) * 2;
                tile2[o] = b1;
                tile2[o + 1] = b2;
            }
        }
    }
}

// ---------------- global top-2 reduce + margin flag ----------------
__global__ void reduce_kernel(const unsigned long long* __restrict__ tile2,
                              int* __restrict__ idxs,
                              int* __restrict__ wl, int* __restrict__ wl_cnt) {
    int i = blockIdx.x * blockDim.x + threadIdx.x;
    if (i >= N_PTS) return;
    unsigned long long b1 = ~0ULL, b2 = ~0ULL;
    #pragma unroll
    for (int j = 0; j < 32; j++) {
        size_t o = ((size_t)j * N_PTS + i) * 2;
        unsigned long long c1 = tile2[o], c2 = tile2[o + 1];
        if (c1 < b1) { b2 = (b1 < c2) ? b1 : c2; b1 = c1; }
        else         { b2 = (b2 < c1) ? b2 : c1; }
    }
    idxs[i] = (int)(unsigned)(b1 & 0xFFFFFFFFu);
    float gap = dec_f32((unsigned)(b2 >> 32)) - dec_f32((unsigned)(b1 >> 32));
    if (gap < MARGIN) {
        int pos = atomicAdd(wl_cnt, 1);
        wl[pos] = i;
    }
}

// ---------------- gather normalized fp32 rows for flagged points -----------
__global__ void gather_kernel(const float* __restrict__ X,
                              const float* __restrict__ rnorm,
                              const int* __restrict__ wl,
                              const int* __restrict__ wl_cnt,
                              float* __restrict__ Xg) {
    int gw = (blockIdx.x * blockDim.x + threadIdx.x) >> 6;
    int lane = threadIdx.x & 63;
    int n = wl_cnt[0];
    if (n > WCAP) n = WCAP;
    for (int pos = gw; pos < n; pos += 2048) {
        int i = wl[pos];
        float rs = rnorm[i];
        const float4* src = (const float4*)(X + (size_t)i * DIM);
        float4* dst = (float4*)(Xg + (size_t)pos * DIM);
        float4 a = src[2 * lane], b = src[2 * lane + 1];
        a.x *= rs; a.y *= rs; a.z *= rs; a.w *= rs;
        b.x *= rs; b.y *= rs; b.z *= rs; b.w *= rs;
        dst[2 * lane] = a;
        dst[2 * lane + 1] = b;
    }
}

// ---------------- tiled fp32 GEMM + argmin over the worklist ----------------
#define BM 128
#define BN 128
#define BK 16

__global__ __launch_bounds__(256) void exact_tile_kernel(
    const float* __restrict__ Xg, const float* __restrict__ C,
    const float* __restrict__ cnorm2, const int* __restrict__ wl_cnt,
    unsigned long long* __restrict__ best64) {
    const int m0 = blockIdx.x * BM;
    int n = wl_cnt[0];
    if (n > WCAP) n = WCAP;
    if (m0 >= n) return;

    __shared__ float As[BK][BM];   // K-major
    __shared__ float Bs[BK][BN];

    const int tid = threadIdx.x;
    const int tx = tid & 15;
    const int ty = tid >> 4;
    const int n0 = blockIdx.y * BN;

    const int f0 = tid;
    const int f1 = tid + 256;
    const int rowA0 = f0 >> 2, kq0 = f0 & 3;
    const int rowA1 = f1 >> 2, kq1 = f1 & 3;
    const float* Abase0 = Xg + (size_t)(m0 + rowA0) * DIM + kq0 * 4;
    const float* Abase1 = Xg + (size_t)(m0 + rowA1) * DIM + kq1 * 4;
    const float* Bbase0 = C + (size_t)(n0 + rowA0) * DIM + kq0 * 4;
    const float* Bbase1 = C + (size_t)(n0 + rowA1) * DIM + kq1 * 4;

    float acc[8][8];
    #pragma unroll
    for (int r = 0; r < 8; r++)
        #pragma unroll
        for (int c = 0; c < 8; c++) acc[r][c] = 0.0f;

    for (int c0 = 0; c0 < DIM; c0 += BK) {
        float4 va0 = *(const float4*)(Abase0 + c0);
        float4 va1 = *(const float4*)(Abase1 + c0);
        float4 vb0 = *(const float4*)(Bbase0 + c0);
        float4 vb1 = *(const float4*)(Bbase1 + c0);
        As[kq0*4+0][rowA0] = va0.x; As[kq0*4+1][rowA0] = va0.y;
        As[kq0*4+2][rowA0] = va0.z; As[kq0*4+3][rowA0] = va0.w;
        As[kq1*4+0][rowA1] = va1.x; As[kq1*4+1][rowA1] = va1.y;
        As[kq1*4+2][rowA1] = va1.z; As[kq1*4+3][rowA1] = va1.w;
        Bs[kq0*4+0][rowA0] = vb0.x; Bs[kq0*4+1][rowA0] = vb0.y;
        Bs[kq0*4+2][rowA0] = vb0.z; Bs[kq0*4+3][rowA0] = vb0.w;
        Bs[kq1*4+0][rowA1] = vb1.x; Bs[kq1*4+1][rowA1] = vb1.y;
        Bs[kq1*4+2][rowA1] = vb1.z; Bs[kq1*4+3][rowA1] = vb1.w;
        __syncthreads();

        #pragma unroll
        for (int t = 0; t < BK; t++) {
            float4 a0 = *(const float4*)&As[t][ty * 8];
            float4 a1 = *(const float4*)&As[t][ty * 8 + 4];
            float4 b0 = *(const float4*)&Bs[t][tx * 8];
            float4 b1 = *(const float4*)&Bs[t][tx * 8 + 4];
            float a[8] = {a0.x, a0.y, a0.z, a0.w, a1.x, a1.y, a1.z, a1.w};
            float b[8] = {b0.x, b0.y, b0.z, b0.w, b1.x, b1.y, b1.z, b1.w};
            #pragma unroll
            for (int r = 0; r < 8; r++)
                #pragma unroll
                for (int c = 0; c < 8; c++)
                    acc[r][c] = fmaf(a[r], b[c], acc[r][c]);
        }
        __syncthreads();
    }

    #pragma unroll
    for (int r = 0; r < 8; r++) {
        float bs = INFINITY;
        int bi = 0x7FFFFFFF;
        #pragma unroll
        for (int c = 0; c < 8; c++) {
            int gc = n0 + tx * 8 + c;
            float s = cnorm2[gc] - 2.0f * acc[r][c];
            if (s < bs) { bs = s; bi = gc; }
        }
        unsigned long long p =
            ((unsigned long long)enc_f32(bs) << 32) | (unsigned)bi;
        #pragma unroll
        for (int off = 1; off < 16; off <<= 1) {
            unsigned long long q = __shfl_xor(p, off);
            if (q < p) p = q;
        }
        if (tx == 0) atomicMin(best64 + m0 + ty * 8 + r, p);
    }
}

// ---------------- write tiled-exact winners back to idxs -------------------
__global__ void writeback_kernel(const unsigned long long* __restrict__ best64,
                                 const int* __restrict__ wl,
                                 const int* __restrict__ wl_cnt,
                                 int* __restrict__ idxs) {
    int pos = blockIdx.x * blockDim.x + threadIdx.x;
    int n = wl_cnt[0];
    if (n > WCAP) n = WCAP;
    if (pos >= n) return;
    idxs[wl[pos]] = (int)(unsigned)(best64[pos] & 0xFFFFFFFFu);
}

// ---------------- serial exact fallback (worklist overflow only) -----------
__global__ __launch_bounds__(256) void exact_serial_kernel(
    const float* __restrict__ X, const float* __restrict__ C,
    const float* __restrict__ rnorm, const float* __restrict__ cnorm2,
    const int* __restrict__ wl, const int* __restrict__ wl_cnt,
    int* __restrict__ idxs) {
    int gw = (blockIdx.x * blockDim.x + threadIdx.x) >> 6;
    int lane = threadIdx.x & 63;
    int n = wl_cnt[0];
    for (int it = WCAP + gw; it < n; it += 1024) {
        int i = wl[it];
        float rs = rnorm[i];
        const float4* xr = (const float4*)(X + (size_t)i * DIM);
        float4 xa = xr[2 * lane], xb = xr[2 * lane + 1];
        xa.x *= rs; xa.y *= rs; xa.z *= rs; xa.w *= rs;
        xb.x *= rs; xb.y *= rs; xb.z *= rs; xb.w *= rs;
        unsigned long long best = ~0ULL;
        for (int k = 0; k < N_CLU; k++) {
            const float4* cr = (const float4*)(C + (size_t)k * DIM);
            float4 ca = cr[2 * lane], cb = cr[2 * lane + 1];
            float d = xa.x*ca.x + xa.y*ca.y + xa.z*ca.z + xa.w*ca.w
                    + xb.x*cb.x + xb.y*cb.y + xb.z*cb.z + xb.w*cb.w;
            #pragma unroll
            for (int off = 32; off > 0; off >>= 1) d += __shfl_xor(d, off);
            float s = cnorm2[k] - 2.0f * d;
            unsigned long long p =
                ((unsigned long long)enc_f32(s) << 32) | (unsigned)k;
            if (p < best) best = p;
        }
        if (lane == 0) idxs[i] = (int)(unsigned)(best & 0xFFFFFFFFu);
    }
}

// ---------------- decode: out_idx + histogram (per-distinct-key atomics) ---
__global__ void decode_kernel(const int* __restrict__ idxs,
                              float* __restrict__ out_idx,
                              int* __restrict__ counts) {
    int i = blockIdx.x * blockDim.x + threadIdx.x;
    if (i >= N_PTS) return;
    int lane = threadIdx.x & 63;
    int idx = idxs[i];
    out_idx[i] = (float)idx;
    // one atomic per distinct key in the wave (skew-proof)
    unsigned long long remaining = __ballot(1);
    while (remaining) {
        int leader = __ffsll((unsigned long long)remaining) - 1;
        int k0 = __shfl(idx, leader);
        unsigned long long mask = __ballot(idx == k0);
        if (lane == leader) atomicAdd(&counts[k0], (int)__popcll(mask));
        remaining &= ~mask;
    }
}

// ---------------- quantized = centroids[idx] (one wave per row) ------------
__global__ void quant_kernel(const float* __restrict__ C,
                             const int* __restrict__ idxs,
                             float* __restrict__ outq) {
    int wave = (blockIdx.x * blockDim.x + threadIdx.x) >> 6;
    int lane = threadIdx.x & 63;
    if (wave >= N_PTS) return;
    int idx = idxs[wave];
    const float4* src = (const float4*)(C + (size_t)idx * DIM);
    float4* dst = (float4*)(outq + (size_t)wave * DIM);
    dst[lane] = src[lane];
    dst[lane + 64] = src[lane + 64];
}

// ---------------- exclusive prefix sum of counts (single block) ------------
__global__ __launch_bounds__(1024) void scan_kernel(const int* __restrict__ counts,
                                                    int* __restrict__ offsets) {
    __shared__ int bufA[N_CLU];
    __shared__ int bufB[N_CLU];
    int t = threadIdx.x;
    bufA[t] = counts[t];
    bufA[t + 1024] = counts[t + 1024];
    __syncthreads();
    int* src = bufA;
    int* dst = bufB;
    for (int d = 1; d < N_CLU; d <<= 1) {
        for (int i = t; i < N_CLU; i += 1024) {
            int v = src[i];
            if (i >= d) v += src[i - d];
            dst[i] = v;
        }
        __syncthreads();
        int* tmp = src; src = dst; dst = tmp;
    }
    for (int i = t; i < N_CLU; i += 1024)
        offsets[i] = (i == 0) ? 0 : src[i - 1];
}

// ---------------- bucket placement (per-distinct-key aggregated rank) ------
__global__ void place_kernel(const int* __restrict__ idxs,
                             const int* __restrict__ offsets,
                             int* __restrict__ cursor,
                             int* __restrict__ bucket,
                             int* __restrict__ bkey) {
    int i = blockIdx.x * blockDim.x + threadIdx.x;
    if (i >= N_PTS) return;
    int lane = threadIdx.x & 63;
    int k = idxs[i];
    int pos = 0;
    // one atomic per distinct key in the wave; members rank via popcount
    unsigned long long remaining = __ballot(1);
    while (remaining) {
        int leader = __ffsll((unsigned long long)remaining) - 1;
        int k0 = __shfl(k, leader);
        unsigned long long mask = __ballot(k == k0);
        int base = 0;
        if (lane == leader) base = atomicAdd(&cursor[k0], (int)__popcll(mask));
        base = __shfl(base, leader);
        if (k == k0)
            pos = offsets[k0] + base +
                  (int)__popcll(mask & ((1ULL << lane) - 1ULL));
        remaining &= ~mask;
    }
    bucket[pos] = i;
    bkey[pos] = k;
}

// ---------------- new_size (single block) ----------------
__global__ __launch_bounds__(1024) void newsize_kernel(
    const float* __restrict__ ema_size, const int* __restrict__ counts,
    float* __restrict__ out_size) {
    __shared__ float red[16];
    __shared__ float nval;
    int t = threadIdx.x;
    float p0 = ema_size[t] * DECAY + (1.0f - DECAY) * (float)counts[t];
    float p1 = ema_size[t + 1024] * DECAY + (1.0f - DECAY) * (float)counts[t + 1024];
    float s = p0 + p1;
    #pragma unroll
    for (int off = 32; off > 0; off >>= 1) s += __shfl_xor(s, off);
    if ((t & 63) == 0) red[t >> 6] = s;
    __syncthreads();
    if (t == 0) {
        float n = 0.0f;
        for (int i = 0; i < 16; i++) n += red[i];
        nval = n;
    }
    __syncthreads();
    float n = nval;
    float denom = n + (float)N_CLU * EPS;
    out_size[t]        = (p0 + EPS) / denom * n;
    out_size[t + 1024] = (p1 + EPS) / denom * n;
}

// ---------------- dw: chunked segmented reduction over sorted bucket -------
#define CHUNK 64
__global__ __launch_bounds__(256) void dw_kernel(
    const float* __restrict__ X, const int* __restrict__ bucket,
    const int* __restrict__ bkey, float* __restrict__ dw) {
    int c0 = blockIdx.x * CHUNK;
    int t = threadIdx.x;
    float accx = 0.0f, accy = 0.0f;
    int prevk = bkey[c0];
    for (int j = 0; j < CHUNK; j++) {
        int pos = c0 + j;
        int k = bkey[pos];
        if (k != prevk) {
            atomicAdd(&dw[(size_t)prevk * DIM + t * 2 + 0], accx);
            atomicAdd(&dw[(size_t)prevk * DIM + t * 2 + 1], accy);
            accx = 0.0f; accy = 0.0f;
            prevk = k;
        }
        int p = bucket[pos];
        float2 v = *(const float2*)(X + (size_t)p * DIM + t * 2);
        accx += v.x; accy += v.y;
    }
    atomicAdd(&dw[(size_t)prevk * DIM + t * 2 + 0], accx);
    atomicAdd(&dw[(size_t)prevk * DIM + t * 2 + 1], accy);
}

// ---------------- new_w, new_centroids ----------------
__global__ void final_kernel(const float* __restrict__ ema_w,
                             const float* __restrict__ dw,
                             const float* __restrict__ new_size,
                             float* __restrict__ out_neww,
                             float* __restrict__ out_newc) {
    int e = blockIdx.x * blockDim.x + threadIdx.x;
    if (e >= N_CLU * DIM) return;
    int k = e >> 9;
    float nw = ema_w[e] * DECAY + (1.0f - DECAY) * dw[e];
    out_neww[e] = nw;
    out_newc[e] = nw / new_size[k];
}

extern "C" void kernel_launch(void* const* d_in, const int* in_sizes, int n_in,
                              void* d_out, int out_size, void* d_ws, size_t ws_size,
                              hipStream_t stream) {
    const float* X        = (const float*)d_in[0];
    const float* C        = (const float*)d_in[1];
    const float* ema_size = (const float*)d_in[2];
    const float* ema_w    = (const float*)d_in[3];
    float* out = (float*)d_out;

    float* out_q    = out + OUT_Q;
    float* out_idx  = out + OUT_IDX;
    float* out_newc = out + OUT_NEWC;
    float* out_sizep= out + OUT_SIZE;
    float* out_neww = out + OUT_NEWW;

    // Big scratch lives inside out_q's 64 MB region, consumed before
    // quant_kernel overwrites it at the end:
    //   Xh    @ [0, 32M)   — prep_x -> dist_mfma
    //   tile2 @ [32M, 48M) — dist_mfma -> reduce
    //   Xg    @ [0, 48M)   — gather -> exact_tile (Xh/tile2 dead by then)
    _Float16* Xh = (_Float16*)out_q;
    unsigned long long* tile2 =
        (unsigned long long*)((char*)out_q + (size_t)N_PTS * DIM * 2);
    float* Xg = (float*)out_q;

    // workspace layout (~7.4 MB)
    char* ws = (char*)d_ws;
    float* rnorm  = (float*)ws;                                    ws += N_PTS * 4;
    float* cnorm2 = (float*)ws;                                    ws += N_CLU * 4;
    int*   idxs   = (int*)ws;                                      ws += N_PTS * 4;
    int*   counts = (int*)ws;                                      ws += N_CLU * 4;
    int*   offsets= (int*)ws;                                      ws += N_CLU * 4;
    int*   cursor = (int*)ws;                                      ws += N_CLU * 4;
    int*   bucket = (int*)ws;                                      ws += N_PTS * 4;
    int*   bkey   = (int*)ws;                                      ws += N_PTS * 4;
    int*   wl     = (int*)ws;                                      ws += N_PTS * 4;
    int*   wl_cnt = (int*)ws;                                      ws += 16;
    float* dw     = (float*)ws;                                    ws += N_CLU * DIM * 4;
    _Float16* Ch  = (_Float16*)ws;                                 ws += (size_t)N_CLU * DIM * 2;
    unsigned long long* best64 = (unsigned long long*)ws;          ws += (size_t)WCAP * 8;

    init_kernel<<<2048, 256, 0, stream>>>(counts, cursor, wl_cnt, dw, best64);
    prep_x_kernel<<<N_PTS / 4, 256, 0, stream>>>(X, rnorm, Xh);
    prep_c_kernel<<<N_CLU / 4, 256, 0, stream>>>(C, cnorm2, Ch);

    dim3 grid(N_PTS / TBM, N_CLU / TBN);
    dist_mfma_kernel<<<grid, 256, 0, stream>>>(Xh, Ch, cnorm2, tile2);

    reduce_kernel<<<N_PTS / 256, 256, 0, stream>>>(tile2, idxs, wl, wl_cnt);
    gather_kernel<<<512, 256, 0, stream>>>(X, rnorm, wl, wl_cnt, Xg);
    dim3 egrid(WCAP / BM, N_CLU / BN);
    exact_tile_kernel<<<egrid, 256, 0, stream>>>(Xg, C, cnorm2, wl_cnt, best64);
    writeback_kernel<<<WCAP / 256, 256, 0, stream>>>(best64, wl, wl_cnt, idxs);
    exact_serial_kernel<<<256, 256, 0, stream>>>(X, C, rnorm, cnorm2, wl, wl_cnt, idxs);

    decode_kernel<<<N_PTS / 256, 256, 0, stream>>>(idxs, out_idx, counts);
    quant_kernel<<<N_PTS / 4, 256, 0, stream>>>(C, idxs, out_q);
    newsize_kernel<<<1, 1024, 0, stream>>>(ema_size, counts, out_sizep);
    scan_kernel<<<1, 1024, 0, stream>>>(counts, offsets);
    place_kernel<<<N_PTS / 256, 256, 0, stream>>>(idxs, offsets, cursor, bucket, bkey);
    dw_kernel<<<N_PTS / CHUNK, 256, 0, stream>>>(X, bucket, bkey, dw);
    final_kernel<<<(N_CLU * DIM) / 256, 256, 0, stream>>>(ema_w, dw, out_sizep, out_neww, out_newc);
}

// Round 8
// 489.023 us; speedup vs baseline: 15.6716x; 1.0504x over previous
//
#include <hip/hip_runtime.h>
#include <hip/hip_bf16.h>
#include <stdint.h>

// Problem constants (match reference)
#define N_PTS    32768
#define N_CLU    2048
#define DIM      512
#define DECAY    0.99f
#define EPS      1e-5f
#define NORM_EPS 1e-12f
#define MARGIN   0.02f   // score-gap threshold for exact fp32 re-check (~7 sigma of fp16 error)
#define WCAP     24576   // worklist rows handled by the tiled exact path

// Output layout (flat f32, reference return order)
#define OUT_Q      0
#define OUT_IDX    (N_PTS*DIM)
#define OUT_NEWC   (OUT_IDX + N_PTS)
#define OUT_SIZE   (OUT_NEWC + N_CLU*DIM)
#define OUT_NEWW   (OUT_SIZE + N_CLU)

typedef _Float16 half8 __attribute__((ext_vector_type(8)));
typedef float f32x4 __attribute__((ext_vector_type(4)));

union H8 { _Float16 h[8]; uint4 u; };

// order-preserving f32 -> u32 encode (min-compatible), and decode
__device__ __forceinline__ unsigned enc_f32(float f) {
    unsigned u = __float_as_uint(f);
    return (u & 0x80000000u) ? ~u : (u | 0x80000000u);
}
__device__ __forceinline__ float dec_f32(unsigned e) {
    unsigned u = (e & 0x80000000u) ? (e & 0x7FFFFFFFu) : ~e;
    return __uint_as_float(u);
}

// async global->LDS, 16B per lane, dest = wave-uniform base + lane*16 (m97)
__device__ __forceinline__ void gload_lds16(const void* g, void* l) {
    __builtin_amdgcn_global_load_lds(
        (const __attribute__((address_space(1))) uint32_t*)g,
        (__attribute__((address_space(3))) uint32_t*)l, 16, 0, 0);
}

// ---------------- init workspace ----------------
__global__ void init_kernel(int* __restrict__ counts,
                            int* __restrict__ cursor,
                            int* __restrict__ wl_cnt,
                            float* __restrict__ dw,
                            unsigned long long* __restrict__ best64) {
    int i = blockIdx.x * blockDim.x + threadIdx.x;
    int stride = gridDim.x * blockDim.x;
    if (i == 0) wl_cnt[0] = 0;
    for (int j = i; j < N_CLU; j += stride) { counts[j] = 0; cursor[j] = 0; }
    for (int j = i; j < N_CLU * DIM; j += stride) dw[j] = 0.0f;
    for (int j = i; j < WCAP; j += stride) best64[j] = 0xFFFFFFFFFFFFFFFFULL;
}

// ---------------- rnorm + normalized X in fp16 (one wave per row) ----------
__global__ void prep_x_kernel(const float* __restrict__ X,
                              float* __restrict__ rnorm,
                              _Float16* __restrict__ Xh) {
    int row = (blockIdx.x * blockDim.x + threadIdx.x) >> 6;
    int lane = threadIdx.x & 63;
    if (row >= N_PTS) return;
    const float4* xr = (const float4*)(X + (size_t)row * DIM);
    float4 a = xr[2 * lane];
    float4 b = xr[2 * lane + 1];
    float ss = a.x*a.x + a.y*a.y + a.z*a.z + a.w*a.w
             + b.x*b.x + b.y*b.y + b.z*b.z + b.w*b.w;
    #pragma unroll
    for (int off = 32; off > 0; off >>= 1) ss += __shfl_xor(ss, off);
    float rs = 1.0f / fmaxf(sqrtf(ss), NORM_EPS);
    if (lane == 0) rnorm[row] = rs;
    H8 o;
    o.h[0] = (_Float16)(a.x * rs); o.h[1] = (_Float16)(a.y * rs);
    o.h[2] = (_Float16)(a.z * rs); o.h[3] = (_Float16)(a.w * rs);
    o.h[4] = (_Float16)(b.x * rs); o.h[5] = (_Float16)(b.y * rs);
    o.h[6] = (_Float16)(b.z * rs); o.h[7] = (_Float16)(b.w * rs);
    *(uint4*)(Xh + (size_t)row * DIM + lane * 8) = o.u;
}

// ---------------- |c|^2 + C in fp16 (one wave per centroid) ----------------
__global__ void prep_c_kernel(const float* __restrict__ C,
                              float* __restrict__ cnorm2,
                              _Float16* __restrict__ Ch) {
    int row = (blockIdx.x * blockDim.x + threadIdx.x) >> 6;
    int lane = threadIdx.x & 63;
    if (row >= N_CLU) return;
    const float4* cr = (const float4*)(C + (size_t)row * DIM);
    float4 a = cr[2 * lane];
    float4 b = cr[2 * lane + 1];
    float ss = a.x*a.x + a.y*a.y + a.z*a.z + a.w*a.w
             + b.x*b.x + b.y*b.y + b.z*b.z + b.w*b.w;
    #pragma unroll
    for (int off = 32; off > 0; off >>= 1) ss += __shfl_xor(ss, off);
    if (lane == 0) cnorm2[row] = ss;
    H8 o;
    o.h[0] = (_Float16)a.x; o.h[1] = (_Float16)a.y;
    o.h[2] = (_Float16)a.z; o.h[3] = (_Float16)a.w;
    o.h[4] = (_Float16)b.x; o.h[5] = (_Float16)b.y;
    o.h[6] = (_Float16)b.z; o.h[7] = (_Float16)b.w;
    *(uint4*)(Ch + (size_t)row * DIM + lane * 8) = o.u;
}

// ---------------- MFMA fp16 GEMM + per-row per-(tile,wc) top-2 -------------
// m97-style: 128x128 tile, BK=32, linear LDS [128][32] halves (frag
// ds_read_b128 is uniform 8 slots/bank = structural minimum), staging via
// global_load_lds width-16 (wave w stages rows [w*16,w*16+16) of each
// 64-row batch; lane l supplies row w*16+(l>>2), kchunk l&3).
#define TBM 128
#define TBN 128
#define TBK 32

__global__ __launch_bounds__(256) void dist_mfma_kernel(
    const _Float16* __restrict__ Xh, const _Float16* __restrict__ Ch,
    const float* __restrict__ cnorm2,
    unsigned long long* __restrict__ tile2) {
    __shared__ _Float16 Ah[TBM * TBK];   // 8 KB, linear: row*32 + k
    __shared__ _Float16 Bh[TBN * TBK];   // 8 KB

    const int tid = threadIdx.x;
    const int m0 = blockIdx.x * TBM;
    const int n0 = blockIdx.y * TBN;

    const int wid = tid >> 6;
    const int l = tid & 63;
    const int wr = wid >> 1, wc = wid & 1;
    const int lr = l & 15, g = l >> 4;

    // staging sources: slot s = wid*64 + l -> row = s>>2 = wid*16 + (l>>2),
    // kchunk = l&3 (8 halves = 16B each). Batch1 = +64 rows.
    const int srow = wid * 16 + (l >> 2);
    const int skq  = l & 3;
    const _Float16* srcA0 = Xh + (size_t)(m0 + srow) * DIM + skq * 8;
    const _Float16* srcA1 = srcA0 + (size_t)64 * DIM;
    const _Float16* srcB0 = Ch + (size_t)(n0 + srow) * DIM + skq * 8;
    const _Float16* srcB1 = srcB0 + (size_t)64 * DIM;
    // wave-uniform LDS bases (elements): batch0 = wid*512, batch1 = 2048 + wid*512
    _Float16* dA0 = Ah + wid * 512;
    _Float16* dA1 = Ah + 2048 + wid * 512;
    _Float16* dB0 = Bh + wid * 512;
    _Float16* dB1 = Bh + 2048 + wid * 512;

    f32x4 acc[4][4];
    #pragma unroll
    for (int m = 0; m < 4; m++)
        #pragma unroll
        for (int n = 0; n < 4; n++) acc[m][n] = (f32x4){0.f, 0.f, 0.f, 0.f};

    for (int k0 = 0; k0 < DIM; k0 += TBK) {
        gload_lds16(srcA0 + k0, dA0);
        gload_lds16(srcA1 + k0, dA1);
        gload_lds16(srcB0 + k0, dB0);
        gload_lds16(srcB1 + k0, dB1);
        __syncthreads();   // compiler drains vmcnt(0) before s_barrier

        half8 af[4], bf[4];
        #pragma unroll
        for (int m = 0; m < 4; m++)
            af[m] = *(const half8*)&Ah[(wr * 64 + m * 16 + lr) * TBK + g * 8];
        #pragma unroll
        for (int n = 0; n < 4; n++)
            bf[n] = *(const half8*)&Bh[(wc * 64 + n * 16 + lr) * TBK + g * 8];
        #pragma unroll
        for (int m = 0; m < 4; m++)
            #pragma unroll
            for (int n = 0; n < 4; n++)
                acc[m][n] = __builtin_amdgcn_mfma_f32_16x16x32_f16(af[m], bf[n], acc[m][n], 0, 0, 0);
        __syncthreads();
    }

    // epilogue: per-row top-2 across this wave's 64 columns
    float cn2[4];
    int coln[4];
    #pragma unroll
    for (int n = 0; n < 4; n++) {
        coln[n] = n0 + wc * 64 + n * 16 + lr;
        cn2[n] = cnorm2[coln[n]];
    }
    const int slot = blockIdx.y * 2 + wc;
    #pragma unroll
    for (int m = 0; m < 4; m++) {
        #pragma unroll
        for (int reg = 0; reg < 4; reg++) {
            unsigned long long b1 = ~0ULL, b2 = ~0ULL;
            #pragma unroll
            for (int n = 0; n < 4; n++) {
                float s = cn2[n] - 2.0f * acc[m][n][reg];
                unsigned long long p =
                    ((unsigned long long)enc_f32(s) << 32) | (unsigned)coln[n];
                if (p < b1) { b2 = b1; b1 = p; }
                else if (p < b2) { b2 = p; }
            }
            #pragma unroll
            for (int off = 1; off < 16; off <<= 1) {
                unsigned long long c1 = __shfl_xor(b1, off);
                unsigned long long c2 = __shfl_xor(b2, off);
                if (c1 < b1) { b2 = (b1 < c2) ? b1 : c2; b1 = c1; }
                else         { b2 = (b2 < c1) ? b2 : c1; }
            }
            if (lr == 0) {
                int R = m0 + wr * 64 + m * 16 + g * 4 + reg;
                size_t o = ((size_t)slot * N_PTS + R) * 2;
                tile2[o] = b1;
                tile2[o + 1] = b2;
            }
        }
    }
}

// ---------------- global top-2 reduce + margin flag ----------------
__global__ void reduce_kernel(const unsigned long long* __restrict__ tile2,
                              int* __restrict__ idxs,
                              int* __restrict__ wl, int* __restrict__ wl_cnt) {
    int i = blockIdx.x * blockDim.x + threadIdx.x;
    if (i >= N_PTS) return;
    unsigned long long b1 = ~0ULL, b2 = ~0ULL;
    #pragma unroll
    for (int j = 0; j < 32; j++) {
        size_t o = ((size_t)j * N_PTS + i) * 2;
        unsigned long long c1 = tile2[o], c2 = tile2[o + 1];
        if (c1 < b1) { b2 = (b1 < c2) ? b1 : c2; b1 = c1; }
        else         { b2 = (b2 < c1) ? b2 : c1; }
    }
    idxs[i] = (int)(unsigned)(b1 & 0xFFFFFFFFu);
    float gap = dec_f32((unsigned)(b2 >> 32)) - dec_f32((unsigned)(b1 >> 32));
    if (gap < MARGIN) {
        int pos = atomicAdd(wl_cnt, 1);
        wl[pos] = i;
    }
}

// ---------------- gather normalized fp32 rows for flagged points -----------
__global__ void gather_kernel(const float* __restrict__ X,
                              const float* __restrict__ rnorm,
                              const int* __restrict__ wl,
                              const int* __restrict__ wl_cnt,
                              float* __restrict__ Xg) {
    int gw = (blockIdx.x * blockDim.x + threadIdx.x) >> 6;
    int lane = threadIdx.x & 63;
    int n = wl_cnt[0];
    if (n > WCAP) n = WCAP;
    for (int pos = gw; pos < n; pos += 2048) {
        int i = wl[pos];
        float rs = rnorm[i];
        const float4* src = (const float4*)(X + (size_t)i * DIM);
        float4* dst = (float4*)(Xg + (size_t)pos * DIM);
        float4 a = src[2 * lane], b = src[2 * lane + 1];
        a.x *= rs; a.y *= rs; a.z *= rs; a.w *= rs;
        b.x *= rs; b.y *= rs; b.z *= rs; b.w *= rs;
        dst[2 * lane] = a;
        dst[2 * lane + 1] = b;
    }
}

// ---------------- tiled fp32 GEMM + argmin over the worklist ----------------
#define BM 128
#define BN 128
#define BK 16

__global__ __launch_bounds__(256) void exact_tile_kernel(
    const float* __restrict__ Xg, const float* __restrict__ C,
    const float* __restrict__ cnorm2, const int* __restrict__ wl_cnt,
    unsigned long long* __restrict__ best64) {
    const int m0 = blockIdx.x * BM;
    int n = wl_cnt[0];
    if (n > WCAP) n = WCAP;
    if (m0 >= n) return;

    __shared__ float As[BK][BM];   // K-major
    __shared__ float Bs[BK][BN];

    const int tid = threadIdx.x;
    const int tx = tid & 15;
    const int ty = tid >> 4;
    const int n0 = blockIdx.y * BN;

    const int f0 = tid;
    const int f1 = tid + 256;
    const int rowA0 = f0 >> 2, kq0 = f0 & 3;
    const int rowA1 = f1 >> 2, kq1 = f1 & 3;
    const float* Abase0 = Xg + (size_t)(m0 + rowA0) * DIM + kq0 * 4;
    const float* Abase1 = Xg + (size_t)(m0 + rowA1) * DIM + kq1 * 4;
    const float* Bbase0 = C + (size_t)(n0 + rowA0) * DIM + kq0 * 4;
    const float* Bbase1 = C + (size_t)(n0 + rowA1) * DIM + kq1 * 4;

    float acc[8][8];
    #pragma unroll
    for (int r = 0; r < 8; r++)
        #pragma unroll
        for (int c = 0; c < 8; c++) acc[r][c] = 0.0f;

    for (int c0 = 0; c0 < DIM; c0 += BK) {
        float4 va0 = *(const float4*)(Abase0 + c0);
        float4 va1 = *(const float4*)(Abase1 + c0);
        float4 vb0 = *(const float4*)(Bbase0 + c0);
        float4 vb1 = *(const float4*)(Bbase1 + c0);
        As[kq0*4+0][rowA0] = va0.x; As[kq0*4+1][rowA0] = va0.y;
        As[kq0*4+2][rowA0] = va0.z; As[kq0*4+3][rowA0] = va0.w;
        As[kq1*4+0][rowA1] = va1.x; As[kq1*4+1][rowA1] = va1.y;
        As[kq1*4+2][rowA1] = va1.z; As[kq1*4+3][rowA1] = va1.w;
        Bs[kq0*4+0][rowA0] = vb0.x; Bs[kq0*4+1][rowA0] = vb0.y;
        Bs[kq0*4+2][rowA0] = vb0.z; Bs[kq0*4+3][rowA0] = vb0.w;
        Bs[kq1*4+0][rowA1] = vb1.x; Bs[kq1*4+1][rowA1] = vb1.y;
        Bs[kq1*4+2][rowA1] = vb1.z; Bs[kq1*4+3][rowA1] = vb1.w;
        __syncthreads();

        #pragma unroll
        for (int t = 0; t < BK; t++) {
            float4 a0 = *(const float4*)&As[t][ty * 8];
            float4 a1 = *(const float4*)&As[t][ty * 8 + 4];
            float4 b0 = *(const float4*)&Bs[t][tx * 8];
            float4 b1 = *(const float4*)&Bs[t][tx * 8 + 4];
            float a[8] = {a0.x, a0.y, a0.z, a0.w, a1.x, a1.y, a1.z, a1.w};
            float b[8] = {b0.x, b0.y, b0.z, b0.w, b1.x, b1.y, b1.z, b1.w};
            #pragma unroll
            for (int r = 0; r < 8; r++)
                #pragma unroll
                for (int c = 0; c < 8; c++)
                    acc[r][c] = fmaf(a[r], b[c], acc[r][c]);
        }
        __syncthreads();
    }

    #pragma unroll
    for (int r = 0; r < 8; r++) {
        float bs = INFINITY;
        int bi = 0x7FFFFFFF;
        #pragma unroll
        for (int c = 0; c < 8; c++) {
            int gc = n0 + tx * 8 + c;
            float s = cnorm2[gc] - 2.0f * acc[r][c];
            if (s < bs) { bs = s; bi = gc; }
        }
        unsigned long long p =
            ((unsigned long long)enc_f32(bs) << 32) | (unsigned)bi;
        #pragma unroll
        for (int off = 1; off < 16; off <<= 1) {
            unsigned long long q = __shfl_xor(p, off);
            if (q < p) p = q;
        }
        if (tx == 0) atomicMin(best64 + m0 + ty * 8 + r, p);
    }
}

// ---------------- write tiled-exact winners back to idxs -------------------
__global__ void writeback_kernel(const unsigned long long* __restrict__ best64,
                                 const int* __restrict__ wl,
                                 const int* __restrict__ wl_cnt,
                                 int* __restrict__ idxs) {
    int pos = blockIdx.x * blockDim.x + threadIdx.x;
    int n = wl_cnt[0];
    if (n > WCAP) n = WCAP;
    if (pos >= n) return;
    idxs[wl[pos]] = (int)(unsigned)(best64[pos] & 0xFFFFFFFFu);
}

// ---------------- serial exact fallback (worklist overflow only) -----------
__global__ __launch_bounds__(256) void exact_serial_kernel(
    const float* __restrict__ X, const float* __restrict__ C,
    const float* __restrict__ rnorm, const float* __restrict__ cnorm2,
    const int* __restrict__ wl, const int* __restrict__ wl_cnt,
    int* __restrict__ idxs) {
    int gw = (blockIdx.x * blockDim.x + threadIdx.x) >> 6;
    int lane = threadIdx.x & 63;
    int n = wl_cnt[0];
    for (int it = WCAP + gw; it < n; it += 1024) {
        int i = wl[it];
        float rs = rnorm[i];
        const float4* xr = (const float4*)(X + (size_t)i * DIM);
        float4 xa = xr[2 * lane], xb = xr[2 * lane + 1];
        xa.x *= rs; xa.y *= rs; xa.z *= rs; xa.w *= rs;
        xb.x *= rs; xb.y *= rs; xb.z *= rs; xb.w *= rs;
        unsigned long long best = ~0ULL;
        for (int k = 0; k < N_CLU; k++) {
            const float4* cr = (const float4*)(C + (size_t)k * DIM);
            float4 ca = cr[2 * lane], cb = cr[2 * lane + 1];
            float d = xa.x*ca.x + xa.y*ca.y + xa.z*ca.z + xa.w*ca.w
                    + xb.x*cb.x + xb.y*cb.y + xb.z*cb.z + xb.w*cb.w;
            #pragma unroll
            for (int off = 32; off > 0; off >>= 1) d += __shfl_xor(d, off);
            float s = cnorm2[k] - 2.0f * d;
            unsigned long long p =
                ((unsigned long long)enc_f32(s) << 32) | (unsigned)k;
            if (p < best) best = p;
        }
        if (lane == 0) idxs[i] = (int)(unsigned)(best & 0xFFFFFFFFu);
    }
}

// ---------------- decode: out_idx + histogram (per-distinct-key atomics) ---
__global__ void decode_kernel(const int* __restrict__ idxs,
                              float* __restrict__ out_idx,
                              int* __restrict__ counts) {
    int i = blockIdx.x * blockDim.x + threadIdx.x;
    if (i >= N_PTS) return;
    int lane = threadIdx.x & 63;
    int idx = idxs[i];
    out_idx[i] = (float)idx;
    unsigned long long remaining = __ballot(1);
    while (remaining) {
        int leader = __ffsll((unsigned long long)remaining) - 1;
        int k0 = __shfl(idx, leader);
        unsigned long long mask = __ballot(idx == k0);
        if (lane == leader) atomicAdd(&counts[k0], (int)__popcll(mask));
        remaining &= ~mask;
    }
}

// ---------------- quantized = centroids[idx] (one wave per row) ------------
__global__ void quant_kernel(const float* __restrict__ C,
                             const int* __restrict__ idxs,
                             float* __restrict__ outq) {
    int wave = (blockIdx.x * blockDim.x + threadIdx.x) >> 6;
    int lane = threadIdx.x & 63;
    if (wave >= N_PTS) return;
    int idx = idxs[wave];
    const float4* src = (const float4*)(C + (size_t)idx * DIM);
    float4* dst = (float4*)(outq + (size_t)wave * DIM);
    dst[lane] = src[lane];
    dst[lane + 64] = src[lane + 64];
}

// ---------------- fused new_size + exclusive scan (single block) -----------
__global__ __launch_bounds__(1024) void sizescan_kernel(
    const float* __restrict__ ema_size, const int* __restrict__ counts,
    float* __restrict__ out_size, int* __restrict__ offsets) {
    __shared__ float red[16];
    __shared__ float nval;
    __shared__ int bufA[N_CLU];
    __shared__ int bufB[N_CLU];
    int t = threadIdx.x;
    int c0 = counts[t], c1 = counts[t + 1024];
    // --- new_size ---
    float p0 = ema_size[t] * DECAY + (1.0f - DECAY) * (float)c0;
    float p1 = ema_size[t + 1024] * DECAY + (1.0f - DECAY) * (float)c1;
    float s = p0 + p1;
    #pragma unroll
    for (int off = 32; off > 0; off >>= 1) s += __shfl_xor(s, off);
    if ((t & 63) == 0) red[t >> 6] = s;
    // --- scan setup ---
    bufA[t] = c0;
    bufA[t + 1024] = c1;
    __syncthreads();
    if (t == 0) {
        float n = 0.0f;
        for (int i = 0; i < 16; i++) n += red[i];
        nval = n;
    }
    int* src = bufA;
    int* dst = bufB;
    for (int d = 1; d < N_CLU; d <<= 1) {
        for (int i = t; i < N_CLU; i += 1024) {
            int v = src[i];
            if (i >= d) v += src[i - d];
            dst[i] = v;
        }
        __syncthreads();
        int* tmp = src; src = dst; dst = tmp;
    }
    for (int i = t; i < N_CLU; i += 1024)
        offsets[i] = (i == 0) ? 0 : src[i - 1];
    float n = nval;
    float denom = n + (float)N_CLU * EPS;
    out_size[t]        = (p0 + EPS) / denom * n;
    out_size[t + 1024] = (p1 + EPS) / denom * n;
}

// ---------------- bucket placement (per-distinct-key aggregated rank) ------
__global__ void place_kernel(const int* __restrict__ idxs,
                             const int* __restrict__ offsets,
                             int* __restrict__ cursor,
                             int* __restrict__ bucket,
                             int* __restrict__ bkey) {
    int i = blockIdx.x * blockDim.x + threadIdx.x;
    if (i >= N_PTS) return;
    int lane = threadIdx.x & 63;
    int k = idxs[i];
    int pos = 0;
    unsigned long long remaining = __ballot(1);
    while (remaining) {
        int leader = __ffsll((unsigned long long)remaining) - 1;
        int k0 = __shfl(k, leader);
        unsigned long long mask = __ballot(k == k0);
        int base = 0;
        if (lane == leader) base = atomicAdd(&cursor[k0], (int)__popcll(mask));
        base = __shfl(base, leader);
        if (k == k0)
            pos = offsets[k0] + base +
                  (int)__popcll(mask & ((1ULL << lane) - 1ULL));
        remaining &= ~mask;
    }
    bucket[pos] = i;
    bkey[pos] = k;
}

// ---------------- dw: chunked segmented reduction over sorted bucket -------
#define CHUNK 64
__global__ __launch_bounds__(256) void dw_kernel(
    const float* __restrict__ X, const int* __restrict__ bucket,
    const int* __restrict__ bkey, float* __restrict__ dw) {
    int c0 = blockIdx.x * CHUNK;
    int t = threadIdx.x;
    float accx = 0.0f, accy = 0.0f;
    int prevk = bkey[c0];
    for (int j = 0; j < CHUNK; j++) {
        int pos = c0 + j;
        int k = bkey[pos];
        if (k != prevk) {
            atomicAdd(&dw[(size_t)prevk * DIM + t * 2 + 0], accx);
            atomicAdd(&dw[(size_t)prevk * DIM + t * 2 + 1], accy);
            accx = 0.0f; accy = 0.0f;
            prevk = k;
        }
        int p = bucket[pos];
        float2 v = *(const float2*)(X + (size_t)p * DIM + t * 2);
        accx += v.x; accy += v.y;
    }
    atomicAdd(&dw[(size_t)prevk * DIM + t * 2 + 0], accx);
    atomicAdd(&dw[(size_t)prevk * DIM + t * 2 + 1], accy);
}

// ---------------- new_w, new_centroids ----------------
__global__ void final_kernel(const float* __restrict__ ema_w,
                             const float* __restrict__ dw,
                             const float* __restrict__ new_size,
                             float* __restrict__ out_neww,
                             float* __restrict__ out_newc) {
    int e = blockIdx.x * blockDim.x + threadIdx.x;
    if (e >= N_CLU * DIM) return;
    int k = e >> 9;
    float nw = ema_w[e] * DECAY + (1.0f - DECAY) * dw[e];
    out_neww[e] = nw;
    out_newc[e] = nw / new_size[k];
}

extern "C" void kernel_launch(void* const* d_in, const int* in_sizes, int n_in,
                              void* d_out, int out_size, void* d_ws, size_t ws_size,
                              hipStream_t stream) {
    const float* X        = (const float*)d_in[0];
    const float* C        = (const float*)d_in[1];
    const float* ema_size = (const float*)d_in[2];
    const float* ema_w    = (const float*)d_in[3];
    float* out = (float*)d_out;

    float* out_q    = out + OUT_Q;
    float* out_idx  = out + OUT_IDX;
    float* out_newc = out + OUT_NEWC;
    float* out_sizep= out + OUT_SIZE;
    float* out_neww = out + OUT_NEWW;

    // Big scratch lives inside out_q's 64 MB region, consumed before
    // quant_kernel overwrites it at the end:
    //   Xh    @ [0, 32M)   — prep_x -> dist_mfma
    //   tile2 @ [32M, 48M) — dist_mfma -> reduce
    //   Xg    @ [0, 48M)   — gather -> exact_tile (Xh/tile2 dead by then)
    _Float16* Xh = (_Float16*)out_q;
    unsigned long long* tile2 =
        (unsigned long long*)((char*)out_q + (size_t)N_PTS * DIM * 2);
    float* Xg = (float*)out_q;

    // workspace layout (~7.4 MB)
    char* ws = (char*)d_ws;
    float* rnorm  = (float*)ws;                                    ws += N_PTS * 4;
    float* cnorm2 = (float*)ws;                                    ws += N_CLU * 4;
    int*   idxs   = (int*)ws;                                      ws += N_PTS * 4;
    int*   counts = (int*)ws;                                      ws += N_CLU * 4;
    int*   offsets= (int*)ws;                                      ws += N_CLU * 4;
    int*   cursor = (int*)ws;                                      ws += N_CLU * 4;
    int*   bucket = (int*)ws;                                      ws += N_PTS * 4;
    int*   bkey   = (int*)ws;                                      ws += N_PTS * 4;
    int*   wl     = (int*)ws;                                      ws += N_PTS * 4;
    int*   wl_cnt = (int*)ws;                                      ws += 16;
    float* dw     = (float*)ws;                                    ws += N_CLU * DIM * 4;
    _Float16* Ch  = (_Float16*)ws;                                 ws += (size_t)N_CLU * DIM * 2;
    unsigned long long* best64 = (unsigned long long*)ws;          ws += (size_t)WCAP * 8;

    init_kernel<<<2048, 256, 0, stream>>>(counts, cursor, wl_cnt, dw, best64);
    prep_x_kernel<<<N_PTS / 4, 256, 0, stream>>>(X, rnorm, Xh);
    prep_c_kernel<<<N_CLU / 4, 256, 0, stream>>>(C, cnorm2, Ch);

    dim3 grid(N_PTS / TBM, N_CLU / TBN);
    dist_mfma_kernel<<<grid, 256, 0, stream>>>(Xh, Ch, cnorm2, tile2);

    reduce_kernel<<<N_PTS / 256, 256, 0, stream>>>(tile2, idxs, wl, wl_cnt);
    gather_kernel<<<512, 256, 0, stream>>>(X, rnorm, wl, wl_cnt, Xg);
    dim3 egrid(WCAP / BM, N_CLU / BN);
    exact_tile_kernel<<<egrid, 256, 0, stream>>>(Xg, C, cnorm2, wl_cnt, best64);
    writeback_kernel<<<WCAP / 256, 256, 0, stream>>>(best64, wl, wl_cnt, idxs);
    exact_serial_kernel<<<256, 256, 0, stream>>>(X, C, rnorm, cnorm2, wl, wl_cnt, idxs);

    decode_kernel<<<N_PTS / 256, 256, 0, stream>>>(idxs, out_idx, counts);
    quant_kernel<<<N_PTS / 4, 256, 0, stream>>>(C, idxs, out_q);
    sizescan_kernel<<<1, 1024, 0, stream>>>(ema_size, counts, out_sizep, offsets);
    place_kernel<<<N_PTS / 256, 256, 0, stream>>>(idxs, offsets, cursor, bucket, bkey);
    dw_kernel<<<N_PTS / CHUNK, 256, 0, stream>>>(X, bucket, bkey, dw);
    final_kernel<<<(N_CLU * DIM) / 256, 256, 0, stream>>>(ema_w, dw, out_sizep, out_neww, out_newc);
}